// Round 3
// baseline (4010.067 us; speedup 1.0000x reference)
//
#include <hip/hip_runtime.h>

typedef _Float16 f16;
typedef _Float16 f16x2 __attribute__((ext_vector_type(2)));
typedef _Float16 f16x8 __attribute__((ext_vector_type(8)));
typedef float    f32x4 __attribute__((ext_vector_type(4)));
typedef unsigned int u32;
typedef unsigned short u16;

#define DEVI static __device__ __forceinline__

static constexpr int LDT = 40;    // lds row stride (halves) for 64x32 tiles (+8 pad)
static constexpr int LDA = 264;   // lds row stride for 64x256 resident A tiles

DEVI float sigf(float x){ return 1.f/(1.f + __expf(-x)); }
DEVI float tanh_c(float x){
  x = fminf(fmaxf(x, -15.f), 15.f);
  float e = __expf(2.f*x);
  return (e - 1.f)/(e + 1.f);
}
DEVI float dot2u(u32 w, u32 h, float c){
#if __has_builtin(__builtin_amdgcn_fdot2)
  return __builtin_amdgcn_fdot2(__builtin_bit_cast(f16x2,w), __builtin_bit_cast(f16x2,h), c, false);
#else
  f16x2 a=__builtin_bit_cast(f16x2,w), b=__builtin_bit_cast(f16x2,h);
  return c + (float)a.x*(float)b.x + (float)a.y*(float)b.y;
#endif
}
DEVI float wmax16(float v){
  #pragma unroll
  for (int m=1;m<16;m<<=1) v = fmaxf(v, __shfl_xor(v, m, 64));
  return v;
}
DEVI float wsum16(float v){
  #pragma unroll
  for (int m=1;m<16;m<<=1) v += __shfl_xor(v, m, 64);
  return v;
}
DEVI float sel4(float v0, float v1, float v2, float v3, int c){
  float lo = (c&1) ? v1 : v0;
  float hi = (c&1) ? v3 : v2;
  return (c&2) ? hi : lo;
}
DEVI f16x8 frag_ld(const f16* p){ return *(const f16x8*)p; }
DEVI void stage_tile(const f16* src, int ld, f16* dst){
  int tid = threadIdx.x; int row = tid>>2, qq = tid&3;
  *(f16x8*)(dst + row*LDT + qq*8) = *(const f16x8*)(src + (size_t)row*ld + qq*8);
}
#define ZERO4(acc) { f32x4 _z = {0.f,0.f,0.f,0.f}; acc[0]=_z; acc[1]=_z; acc[2]=_z; acc[3]=_z; }

// 64x64 NT MFMA tile: A (64 x K, row-major lda), B^T (64 x K, row-major ldb)
DEVI void gemm64(const f16* A, int lda, const f16* Bm, int ldb, int K,
                 f16* lA, f16* lB, f32x4 acc[4]){
  const int lane = threadIdx.x & 63, wv = threadIdx.x >> 6;
  const int l15 = lane & 15, kq = lane >> 4;
  for (int k0=0; k0<K; k0+=32){
    __syncthreads();
    stage_tile(A + k0, lda, lA);
    stage_tile(Bm + k0, ldb, lB);
    __syncthreads();
    f16x8 af = frag_ld(lA + (16*wv + l15)*LDT + kq*8);
    #pragma unroll
    for (int nt=0; nt<4; nt++){
      f16x8 bf = frag_ld(lB + (16*nt + l15)*LDT + kq*8);
      acc[nt] = __builtin_amdgcn_mfma_f32_16x16x32_f16(af, bf, acc[nt], 0,0,0);
    }
  }
}

// ---------------- small prep kernels ----------------
__global__ void k_cvt(const float* __restrict__ s, f16* __restrict__ d, int n){
  int i = blockIdx.x*256 + threadIdx.x;
  if (i < n) d[i] = (f16)s[i];
}
// gconv (K,Fi,Fo) -> gcT (Fo, K*Fi)
__global__ void k_gconvT(const float* __restrict__ s, f16* __restrict__ d){
  int id = blockIdx.x;            // k*256+fi : 1280
  int fo = threadIdx.x;           // 256
  d[(size_t)fo*1280 + id] = (f16)s[(size_t)id*256 + fo];
}
// gdecode (F,V) -> gdT (VP=2048, F) zero-padded rows
__global__ void k_gdecT(const float* __restrict__ s, f16* __restrict__ d){
  int v = blockIdx.x, f = threadIdx.x;    // 2048 x 256
  f16 val = (f16)0.f;
  if (v < 2000) val = (f16)s[(size_t)f*2000 + v];
  d[(size_t)v*256 + f] = val;
}
// e_pad[b][p][f] = p in [2,514) ? tanh(gembed[xs[b][p-2]][f]) : 0
__global__ void k_epad(const int* __restrict__ xs, const float* __restrict__ gemb, f16* __restrict__ epad){
  int id = blockIdx.x;            // b*516+p
  int f = threadIdx.x;
  int b = id / 516, p = id % 516;
  float v = 0.f;
  if (p >= 2 && p < 514){ int idx = xs[b*512 + p - 2]; v = tanh_c(gemb[(size_t)idx*256 + f]); }
  epad[(size_t)id*256 + f] = (f16)v;
}
// enc/dec embeddings with <P mask
__global__ void k_embx(const int* __restrict__ xs, const int* __restrict__ ys,
                       const float* __restrict__ eemb, const float* __restrict__ demb,
                       f16* __restrict__ xo, f16* __restrict__ yo){
  int id = blockIdx.x; int f = threadIdx.x;  // 2*32*512 blocks x 128
  bool dec = id >= 32*512; int id2 = dec ? id - 32*512 : id;
  int idx = dec ? ys[id2] : xs[id2];
  if (idx < 4) idx = 0;
  const float* src = (dec ? demb : eemb) + (size_t)idx*128;
  (dec ? yo : xo)[(size_t)id2*128 + f] = (f16)src[f];
}

// Whh (1024x256 f32) -> 2-way split for k_lstm3.
// thread mapping: c = tid&3, r = tid>>2; w-index i in [0,1024):
//   element = Whh[(r + 64*(i>>6))*256 + c*64 + (i&63)]
// i <  768           -> Wreg[(i>>3)*256 + tid]        (register-resident, 96 uint4)
// 768 <= i < 1024    -> Wlds[((i-768)>>3)*256 + tid]  (LDS-resident, 32 uint4)
__global__ void k_wsplit(const float* __restrict__ Whh, uint4* __restrict__ Wreg,
                         uint4* __restrict__ Wlds){
  const int kb = blockIdx.x;          // 0..127
  const int tid = threadIdx.x;        // 0..255
  const int c = tid & 3, r = tid >> 2;
  f16 tmp[8];
  #pragma unroll
  for (int e8=0; e8<8; e8++){
    int i = kb*8 + e8;
    int row = r + 64*(i>>6);
    int col = c*64 + (i&63);
    tmp[e8] = (f16)Whh[(size_t)row*256 + col];
  }
  uint4 v = *(uint4*)tmp;
  int i0 = kb*8;
  if (i0 < 768)      Wreg[(size_t)(i0>>3)*256 + tid] = v;
  else               Wlds[(size_t)((i0-768)>>3)*256 + tid] = v;
}

// ---------------- GEMM kernels ----------------
__global__ __launch_bounds__(256,4) void k_conv(const f16* __restrict__ epad, const f16* __restrict__ gcT, f16* __restrict__ tf){
  __shared__ f16 lA[64*LDT], lB[64*LDT];
  const int m0 = blockIdx.x*64, n0 = blockIdx.y*64;
  const int b = m0 >> 9, n = m0 & 511;
  f32x4 acc[4]; ZERO4(acc);
  gemm64(epad + ((size_t)b*516 + n)*256, 256, gcT + (size_t)n0*1280, 1280, 1280, lA, lB, acc);
  const int lane=threadIdx.x&63, wv=threadIdx.x>>6, l15=lane&15, kq=lane>>4;
  #pragma unroll
  for (int nt=0;nt<4;nt++)
    #pragma unroll
    for (int r=0;r<4;r++)
      tf[(size_t)(m0 + 16*wv + 4*kq + r)*256 + n0 + nt*16 + l15] = (f16)tanh_c(acc[nt][r]);
}

__global__ __launch_bounds__(256,4) void k_u(const f16* __restrict__ X, const f16* __restrict__ Wih,
                                             const float* __restrict__ bias, f16* __restrict__ U){
  __shared__ f16 lA[64*LDT], lB[64*LDT];
  const int m0 = blockIdx.x*64, n0 = blockIdx.y*64;
  f32x4 acc[4]; ZERO4(acc);
  gemm64(X + (size_t)m0*128, 128, Wih + (size_t)n0*128, 128, 128, lA, lB, acc);
  const int lane=threadIdx.x&63, wv=threadIdx.x>>6, l15=lane&15, kq=lane>>4;
  #pragma unroll
  for (int nt=0;nt<4;nt++){
    float bv = bias[n0 + nt*16 + l15];
    #pragma unroll
    for (int r=0;r<4;r++)
      U[(size_t)(m0 + 16*wv + 4*kq + r)*1024 + n0 + nt*16 + l15] = (f16)(acc[nt][r] + bv);
  }
}

__global__ __launch_bounds__(256,4) void k_th(const f16* __restrict__ henh, const f16* __restrict__ Tf, f16* __restrict__ Th){
  __shared__ f16 lA[64*LDT], lB[64*LDT];
  const int m0 = blockIdx.x*64, n0 = blockIdx.y*64;
  f32x4 acc[4]; ZERO4(acc);
  gemm64(henh + (size_t)m0*512, 512, Tf + (size_t)n0*512, 512, 512, lA, lB, acc);
  const int lane=threadIdx.x&63, wv=threadIdx.x>>6, l15=lane&15, kq=lane>>4;
  #pragma unroll
  for (int nt=0;nt<4;nt++)
    #pragma unroll
    for (int r=0;r<4;r++)
      Th[(size_t)(m0 + 16*wv + 4*kq + r)*256 + n0 + nt*16 + l15] = (f16)acc[nt][r];
}

// pass1: online row-max + sum-exp of logits = tf @ gdT^T over N=2048 (cols>=2000 masked)
__global__ __launch_bounds__(256,2) void k_pass1(const f16* __restrict__ tf, const f16* __restrict__ gdT,
                                                 float* __restrict__ mxp, float* __restrict__ sep){
  __shared__ f16 lA[64*LDA];
  __shared__ f16 lB[64*LDT];
  __shared__ float mx_s[64], se_s[64];
  const int mt = blockIdx.x, ns = blockIdx.y;
  const int tid = threadIdx.x, lane=tid&63, wv=tid>>6, l15=lane&15, kq=lane>>4;
  {
    const f16* A = tf + (size_t)mt*64*256;
    int row = tid>>2, qq = tid&3;
    #pragma unroll
    for (int c=0;c<8;c++)
      *(f16x8*)(lA + row*LDA + c*32 + qq*8) = *(const f16x8*)(A + (size_t)row*256 + c*32 + qq*8);
  }
  if (tid < 64){ mx_s[tid] = -1e30f; se_s[tid] = 0.f; }
  __syncthreads();
  for (int nc=0; nc<8; nc++){
    const int nbase = ns*512 + nc*64;
    const f16* Bm = gdT + (size_t)nbase*256;
    f32x4 acc[4]; ZERO4(acc);
    for (int k0=0; k0<256; k0+=32){
      __syncthreads();
      stage_tile(Bm + k0, 256, lB);
      __syncthreads();
      f16x8 af = frag_ld(lA + (16*wv + l15)*LDA + k0 + kq*8);
      #pragma unroll
      for (int nt=0; nt<4; nt++){
        f16x8 bf = frag_ld(lB + (16*nt + l15)*LDT + kq*8);
        acc[nt] = __builtin_amdgcn_mfma_f32_16x16x32_f16(af, bf, acc[nt], 0,0,0);
      }
    }
    #pragma unroll
    for (int r=0;r<4;r++){
      float av[4]; float cm = -1e30f;
      #pragma unroll
      for (int nt=0;nt<4;nt++){
        int gcol = nbase + nt*16 + l15;
        float a = (gcol < 2000) ? acc[nt][r] : -1e30f;
        av[nt] = a; cm = fmaxf(cm, a);
      }
      cm = wmax16(cm);
      int rr = 16*wv + 4*kq + r;
      float old = mx_s[rr];
      float nm = fmaxf(old, cm);
      float ss = 0.f;
      #pragma unroll
      for (int nt=0;nt<4;nt++) ss += __expf(av[nt] - nm);
      ss = wsum16(ss);
      if (l15 == 0){
        se_s[rr] = se_s[rr]*__expf(old - nm) + ss;
        mx_s[rr] = nm;
      }
    }
  }
  __syncthreads();
  if (tid < 64){
    mxp[(size_t)ns*16384 + mt*64 + tid] = mx_s[tid];
    sep[(size_t)ns*16384 + mt*64 + tid] = se_s[tid];
  }
}

__global__ void k_comb1(const float* __restrict__ mxp, const float* __restrict__ sep,
                        float* __restrict__ mx, float* __restrict__ se){
  int m = blockIdx.x*256 + threadIdx.x;
  float best = -1e30f;
  #pragma unroll
  for (int k=0;k<4;k++) best = fmaxf(best, mxp[(size_t)k*16384 + m]);
  float s = 0.f;
  #pragma unroll
  for (int k=0;k<4;k++) s += sep[(size_t)k*16384 + m] * __expf(mxp[(size_t)k*16384 + m] - best);
  mx[m] = best; se[m] = s;
}

// pass2: scoresT[b][j][i] = exp(logit(i, ys[b][j]) - mx)/se  via gathered-row GEMM
__global__ __launch_bounds__(256,4) void k_pass2(const f16* __restrict__ tf, const f16* __restrict__ gdT,
                                                 const int* __restrict__ ys, const float* __restrict__ mx,
                                                 const float* __restrict__ se, f16* __restrict__ scT){
  __shared__ f16 lA[64*LDT], lB[64*LDT];
  __shared__ int jv[64];
  const int it = blockIdx.x, jt = blockIdx.y, b = blockIdx.z;
  const int tid = threadIdx.x, lane=tid&63, wv=tid>>6, l15=lane&15, kq=lane>>4;
  if (tid<64) jv[tid] = ys[b*512 + jt*64 + tid];
  const f16* A = tf + ((size_t)b*512 + it*64)*256;
  f32x4 acc[4]; ZERO4(acc);
  for (int k0=0;k0<256;k0+=32){
    __syncthreads();
    stage_tile(A + k0, 256, lA);
    { int row=tid>>2, qq=tid&3;
      *(f16x8*)(lB + row*LDT + qq*8) = *(const f16x8*)(gdT + (size_t)jv[row]*256 + k0 + qq*8); }
    __syncthreads();
    f16x8 af = frag_ld(lA + (16*wv+l15)*LDT + kq*8);
    #pragma unroll
    for (int nt=0;nt<4;nt++){
      f16x8 bf = frag_ld(lB + (16*nt+l15)*LDT + kq*8);
      acc[nt] = __builtin_amdgcn_mfma_f32_16x16x32_f16(af, bf, acc[nt], 0,0,0);
    }
  }
  float mxv[4], rsev[4];
  #pragma unroll
  for (int r=0;r<4;r++){
    int i_ = it*64 + 16*wv + 4*kq + r;
    mxv[r] = mx[b*512 + i_];
    rsev[r] = 1.f / se[b*512 + i_];
  }
  #pragma unroll
  for (int nt=0;nt<4;nt++){
    int j_ = jt*64 + nt*16 + l15;
    #pragma unroll
    for (int r=0;r<4;r++){
      int i_ = it*64 + 16*wv + 4*kq + r;
      scT[((size_t)b*512 + j_)*512 + i_] = (f16)(__expf(acc[nt][r] - mxv[r]) * rsev[r]);
    }
  }
}

// fused eij -> softmax over i -> <scores,align> -> partials (i split in 2)
__global__ __launch_bounds__(256,2) void k_final(const f16* __restrict__ hdec, const f16* __restrict__ Th,
                                                 const f16* __restrict__ scT,
                                                 float* __restrict__ pmx, float* __restrict__ pden, float* __restrict__ pnum){
  __shared__ f16 lA[64*LDA];
  __shared__ f16 lB[64*LDT];
  __shared__ float mx_s[64], den_s[64], num_s[64];
  const int is = blockIdx.x, jt = blockIdx.y, b = blockIdx.z;
  const int tid = threadIdx.x, lane=tid&63, wv=tid>>6, l15=lane&15, kq=lane>>4;
  {
    const f16* A = hdec + ((size_t)b*512 + jt*64)*256;
    int row = tid>>2, qq = tid&3;
    #pragma unroll
    for (int c=0;c<8;c++)
      *(f16x8*)(lA + row*LDA + c*32 + qq*8) = *(const f16x8*)(A + (size_t)row*256 + c*32 + qq*8);
  }
  if (tid<64){ mx_s[tid]=-1e30f; den_s[tid]=0.f; num_s[tid]=0.f; }
  __syncthreads();
  for (int ic=0; ic<4; ic++){
    const int i0 = is*256 + ic*64;
    const f16* Bm = Th + ((size_t)b*512 + i0)*256;
    f32x4 acc[4]; ZERO4(acc);
    for (int k0=0;k0<256;k0+=32){
      __syncthreads();
      stage_tile(Bm + k0, 256, lB);
      __syncthreads();
      f16x8 af = frag_ld(lA + (16*wv+l15)*LDA + k0 + kq*8);
      #pragma unroll
      for (int nt=0;nt<4;nt++){
        f16x8 bf = frag_ld(lB + (16*nt+l15)*LDT + kq*8);
        acc[nt] = __builtin_amdgcn_mfma_f32_16x16x32_f16(af, bf, acc[nt], 0,0,0);
      }
    }
    #pragma unroll
    for (int r=0;r<4;r++){
      int jl = 16*wv + 4*kq + r;
      float av[4]; float cm=-1e30f;
      #pragma unroll
      for (int nt=0;nt<4;nt++){ av[nt]=acc[nt][r]; cm=fmaxf(cm,av[nt]); }
      cm = wmax16(cm);
      float old = mx_s[jl], nm = fmaxf(old, cm);
      float ds=0.f, nsum=0.f;
      const size_t srow = ((size_t)b*512 + jt*64 + jl)*512;
      #pragma unroll
      for (int nt=0;nt<4;nt++){
        float e = __expf(av[nt]-nm);
        float sc = (float)scT[srow + i0 + nt*16 + l15];
        ds += e; nsum += sc*e;
      }
      ds = wsum16(ds); nsum = wsum16(nsum);
      if (l15==0){
        float fac = __expf(old-nm);
        den_s[jl] = den_s[jl]*fac + ds;
        num_s[jl] = num_s[jl]*fac + nsum;
        mx_s[jl] = nm;
      }
    }
  }
  __syncthreads();
  if (tid<64){
    size_t idx = (((size_t)b*512) + jt*64 + tid)*2 + is;
    pmx[idx]=mx_s[tid]; pden[idx]=den_s[tid]; pnum[idx]=num_s[tid];
  }
}

__global__ void k_comb2(const float* __restrict__ pmx, const float* __restrict__ pden,
                        const float* __restrict__ pnum, float* __restrict__ out){
  const int b = blockIdx.x, j = threadIdx.x;    // 32 x 512
  size_t base = ((size_t)b*512 + j)*2;
  float m0=pmx[base], m1=pmx[base+1];
  float m = fmaxf(m0,m1);
  float e0=__expf(m0-m), e1=__expf(m1-m);
  float den = pden[base]*e0 + pden[base+1]*e1;
  float num = pnum[base]*e0 + pnum[base+1]*e1;
  float lp = __logf(num) - __logf(den);
  __shared__ float red[512];
  red[j] = lp;
  __syncthreads();
  for (int st=256; st>0; st>>=1){ if (j<st) red[j]+=red[j+st]; __syncthreads(); }
  if (j==0) atomicAdd(out, -red[0]);
}

// ---------------- LSTM v3: one WG/sequence; weights 96 uint4 in regs + 32 uint4 in LDS ----------------
// 256 threads; thread (c=tid&3, r=tid>>2) owns rows {r+64m, m=0..15} x K-chunk [c*64, c*64+64).
// Cross-chunk partials reduced via shfl_xor(1),(2) (all 4 get the sum); thread c then computes
// hidden unit hid=c*64+r (gate rows m=g*4+c). h triple-buffered in LDS; 1 barrier/step.
static constexpr int HS3 = 296;  // halves per h buffer (16B-aligned stride)

__global__ __launch_bounds__(256,1) void k_lstm3(
    const u16* __restrict__ U, const uint4* __restrict__ Wreg, const uint4* __restrict__ Wlds,
    u16* __restrict__ hout, float* __restrict__ hTcT,
    u16* __restrict__ hdec0, int nsteps, int mode)
{
  __shared__ uint4 wl[32*256];               // 128 KiB LDS-resident weights
  __shared__ __align__(16) f16 h3[3*HS3];    // triple-buffered h

  const int tid = threadIdx.x;
  const int c = tid & 3, r = tid >> 2;
  const int hid = c*64 + r;
  int dir = 0, b = blockIdx.x;
  if (mode == 0){ dir = (b >= 32) ? 1 : 0; b &= 31; }

  uint4 w[96];                               // 384 register slots (VGPR+AGPR)
  #pragma unroll
  for (int k8=0;k8<96;k8++) w[k8] = Wreg[(size_t)k8*256 + tid];
  #pragma unroll
  for (int j=0;j<32;j++) wl[j*256 + tid] = Wlds[(size_t)j*256 + tid];

  float cst = 0.f;
  if (mode == 0){
    h3[c*72 + r] = (f16)0.f;
  } else {
    h3[c*72 + r] = (f16)hTcT[(size_t)b*512 + hid];
    cst = hTcT[(size_t)b*512 + 256 + hid];
  }
  __syncthreads();

  int rb = 0;
  #pragma unroll 1
  for (int t=0; t<nsteps; ++t){
    const int tpos = dir ? (nsteps-1-t) : t;
    const size_t ubase = ((size_t)b*512 + tpos)*1024;

    // U prefetch: the 4 gate pre-activations for this thread's hidden unit
    u16 uv[4];
    #pragma unroll
    for (int g=0;g<4;g++) uv[g] = U[ubase + g*256 + hid];

    // h fragment for this thread's K-chunk
    const f16* hb = h3 + rb*HS3 + c*72;
    uint4 hreg[8];
    #pragma unroll
    for (int q=0;q<8;q++) hreg[q] = *(const uint4*)(hb + q*8);

    float acc[16];
    #pragma unroll
    for (int m=0;m<16;m++) acc[m]=0.f;

    // register part: i = k8*8 < 768; m = k8>>3, q = k8&7
    #pragma unroll
    for (int k8=0;k8<96;k8++){
      const int m = k8>>3, q = k8&7;
      uint4 wv4 = w[k8]; uint4 hh = hreg[q];
      acc[m] = dot2u(wv4.x, hh.x, acc[m]);
      acc[m] = dot2u(wv4.y, hh.y, acc[m]);
      acc[m] = dot2u(wv4.z, hh.z, acc[m]);
      acc[m] = dot2u(wv4.w, hh.w, acc[m]);
    }
    // LDS part: i = 768+8j; m = 12+(j>>3), q = j&7
    #pragma unroll
    for (int j=0;j<32;j++){
      const int m = 12 + (j>>3), q = j&7;
      uint4 wv4 = wl[j*256 + tid]; uint4 hh = hreg[q];
      acc[m] = dot2u(wv4.x, hh.x, acc[m]);
      acc[m] = dot2u(wv4.y, hh.y, acc[m]);
      acc[m] = dot2u(wv4.z, hh.z, acc[m]);
      acc[m] = dot2u(wv4.w, hh.w, acc[m]);
    }

    // cross-chunk reduce (xor over the 4 K-chunks; every thread ends with full sums)
    #pragma unroll
    for (int m=0;m<16;m++){
      acc[m] += __shfl_xor(acc[m], 1, 64);
      acc[m] += __shfl_xor(acc[m], 2, 64);
    }

    // epilogue: every thread handles unit hid = c*64+r; gate g uses acc[g*4+c]
    float zi = sel4(acc[0],  acc[1],  acc[2],  acc[3],  c) + (float)__builtin_bit_cast(f16, uv[0]);
    float zf = sel4(acc[4],  acc[5],  acc[6],  acc[7],  c) + (float)__builtin_bit_cast(f16, uv[1]);
    float zg = sel4(acc[8],  acc[9],  acc[10], acc[11], c) + (float)__builtin_bit_cast(f16, uv[2]);
    float zo = sel4(acc[12], acc[13], acc[14], acc[15], c) + (float)__builtin_bit_cast(f16, uv[3]);
    cst = sigf(zf)*cst + sigf(zi)*tanh_c(zg);
    float h = sigf(zo)*tanh_c(cst);
    f16 hf = (f16)h;

    int nb = rb + 1; if (nb == 3) nb = 0;
    h3[nb*HS3 + c*72 + r] = hf;

    if (mode == 0){
      hout[((size_t)b*512 + tpos)*512 + dir*256 + hid] = __builtin_bit_cast(u16, hf);
      if (!dir && t == nsteps-1){
        hdec0[(size_t)b*512*256 + hid] = __builtin_bit_cast(u16, hf);
        hTcT[(size_t)b*512 + hid] = h;
        hTcT[(size_t)b*512 + 256 + hid] = cst;
      }
    } else {
      hout[((size_t)b*512 + (t+1))*256 + hid] = __builtin_bit_cast(u16, hf);
    }
    __syncthreads();   // h(t+1) visible; triple-buffer prevents read/write races
    rb = nb;
  }
}

// ---------------- host ----------------
extern "C" void kernel_launch(void* const* d_in, const int* in_sizes, int n_in,
                              void* d_out, int out_size, void* d_ws, size_t ws_size,
                              hipStream_t stream)
{
  (void)in_sizes; (void)n_in; (void)out_size;
  const int*   xs    = (const int*)d_in[0];
  const int*   ys    = (const int*)d_in[1];
  const float* gemb  = (const float*)d_in[2];
  const float* gconv = (const float*)d_in[3];
  const float* gdec  = (const float*)d_in[4];
  const float* eemb  = (const float*)d_in[5];
  const float* demb  = (const float*)d_in[6];
  const float* eWih  = (const float*)d_in[7];
  const float* eWhh  = (const float*)d_in[8];
  const float* eb    = (const float*)d_in[9];
  const float* dWih  = (const float*)d_in[10];
  const float* dWhh  = (const float*)d_in[11];
  const float* db    = (const float*)d_in[12];
  const float* Tm    = (const float*)d_in[13];

  char* wsb = (char*)d_ws;
  size_t off = 0;
  auto take = [&](size_t bytes)->char*{ char* p = wsb + off; off += (bytes + 255) & ~(size_t)255; return p; };
  f16* epad  = (f16*)take((size_t)32*516*256*2);
  f16* tf    = (f16*)take((size_t)32*512*256*2);
  f16* xemb  = (f16*)take((size_t)32*512*128*2);
  f16* yemb  = (f16*)take((size_t)32*512*128*2);
  f16* Uenc  = (f16*)take((size_t)32*512*1024*2);
  f16* Udec  = (f16*)take((size_t)32*512*1024*2);
  f16* henh  = (f16*)take((size_t)32*512*512*2);
  f16* hdec  = (f16*)take((size_t)32*512*256*2);
  f16* Th    = (f16*)take((size_t)32*512*256*2);
  f16* scT   = (f16*)take((size_t)32*512*512*2);
  float* mx  = (float*)take((size_t)16384*4);
  float* se  = (float*)take((size_t)16384*4);
  float* mxp = (float*)take((size_t)4*16384*4);
  float* sep = (float*)take((size_t)4*16384*4);
  float* pmx = (float*)take((size_t)32*512*2*4);
  float* pden= (float*)take((size_t)32*512*2*4);
  float* pnum= (float*)take((size_t)32*512*2*4);
  float* hTcT= (float*)take((size_t)32*512*4);
  f16* Wihe  = (f16*)take((size_t)1024*128*2);
  f16* Wihd  = (f16*)take((size_t)1024*128*2);
  f16* Tf    = (f16*)take((size_t)256*512*2);
  f16* gcT   = (f16*)take((size_t)256*1280*2);
  f16* gdT   = (f16*)take((size_t)2048*256*2);
  uint4* Wrege = (uint4*)take((size_t)96*256*16);
  uint4* Wldse = (uint4*)take((size_t)32*256*16);
  uint4* Wregd = (uint4*)take((size_t)96*256*16);
  uint4* Wldsd = (uint4*)take((size_t)32*256*16);
  if (off > ws_size) return;  // insufficient scratch -> visible as wrong answer

  hipMemsetAsync(d_out, 0, sizeof(float), stream);

  // weight conversions / splits
  k_cvt<<<dim3(512),  256, 0, stream>>>(eWih, Wihe, 1024*128);
  k_cvt<<<dim3(512),  256, 0, stream>>>(dWih, Wihd, 1024*128);
  k_cvt<<<dim3(512),  256, 0, stream>>>(Tm,   Tf,   256*512);
  k_gconvT<<<dim3(1280), 256, 0, stream>>>(gconv, gcT);
  k_gdecT <<<dim3(2048), 256, 0, stream>>>(gdec, gdT);
  k_wsplit<<<dim3(128), 256, 0, stream>>>(eWhh, Wrege, Wldse);
  k_wsplit<<<dim3(128), 256, 0, stream>>>(dWhh, Wregd, Wldsd);

  // embeddings
  k_epad<<<dim3(32*516), 256, 0, stream>>>(xs, gemb, epad);
  k_embx<<<dim3(2*32*512), 128, 0, stream>>>(xs, ys, eemb, demb, xemb, yemb);

  // G-stack
  k_conv<<<dim3(256,4), 256, 0, stream>>>(epad, gcT, tf);
  k_pass1<<<dim3(256,4), 256, 0, stream>>>(tf, gdT, mxp, sep);
  k_comb1<<<dim3(64), 256, 0, stream>>>(mxp, sep, mx, se);
  k_pass2<<<dim3(8,8,32), 256, 0, stream>>>(tf, gdT, ys, mx, se, scT);

  // LSTM input-gate precompute
  k_u<<<dim3(256,16), 256, 0, stream>>>(xemb, Wihe, eb, Uenc);
  k_u<<<dim3(256,16), 256, 0, stream>>>(yemb, Wihd, db, Udec);

  // recurrences (single-WG per sequence; no cross-CU sync, no scratch spills)
  k_lstm3<<<dim3(64), 256, 0, stream>>>((const u16*)Uenc, Wrege, Wldse, (u16*)henh, hTcT, (u16*)hdec, 512, 0);
  k_lstm3<<<dim3(32), 256, 0, stream>>>((const u16*)Udec, Wregd, Wldsd, (u16*)hdec, hTcT, (u16*)hdec, 511, 1);

  // alignment
  k_th<<<dim3(256,4), 256, 0, stream>>>(henh, Tf, Th);
  k_final<<<dim3(2,8,32), 256, 0, stream>>>(hdec, Th, scT, pmx, pden, pnum);
  k_comb2<<<dim3(32), 512, 0, stream>>>(pmx, pden, pnum, (float*)d_out);
}

// Round 4
// 3434.890 us; speedup vs baseline: 1.1675x; 1.1675x over previous
//
#include <hip/hip_runtime.h>

typedef _Float16 f16;
typedef _Float16 f16x2 __attribute__((ext_vector_type(2)));
typedef _Float16 f16x8 __attribute__((ext_vector_type(8)));
typedef float    f32x4 __attribute__((ext_vector_type(4)));
typedef unsigned int u32;
typedef unsigned short u16;

#define DEVI static __device__ __forceinline__

static constexpr int LDT = 40;    // lds row stride (halves) for 64x32 tiles (+8 pad)
static constexpr int LDA = 264;   // lds row stride for 64x256 resident A tiles

DEVI float sigf(float x){ return 1.f/(1.f + __expf(-x)); }
DEVI float tanh_c(float x){
  x = fminf(fmaxf(x, -15.f), 15.f);
  float e = __expf(2.f*x);
  return (e - 1.f)/(e + 1.f);
}
DEVI float dot2u(u32 w, u32 h, float c){
#if __has_builtin(__builtin_amdgcn_fdot2)
  return __builtin_amdgcn_fdot2(__builtin_bit_cast(f16x2,w), __builtin_bit_cast(f16x2,h), c, false);
#else
  f16x2 a=__builtin_bit_cast(f16x2,w), b=__builtin_bit_cast(f16x2,h);
  return c + (float)a.x*(float)b.x + (float)a.y*(float)b.y;
#endif
}
DEVI float wmax16(float v){
  #pragma unroll
  for (int m=1;m<16;m<<=1) v = fmaxf(v, __shfl_xor(v, m, 64));
  return v;
}
DEVI float wsum16(float v){
  #pragma unroll
  for (int m=1;m<16;m<<=1) v += __shfl_xor(v, m, 64);
  return v;
}
DEVI f16x8 frag_ld(const f16* p){ return *(const f16x8*)p; }
DEVI void stage_tile(const f16* src, int ld, f16* dst){
  int tid = threadIdx.x; int row = tid>>2, qq = tid&3;
  *(f16x8*)(dst + row*LDT + qq*8) = *(const f16x8*)(src + (size_t)row*ld + qq*8);
}
#define ZERO4(acc) { f32x4 _z = {0.f,0.f,0.f,0.f}; acc[0]=_z; acc[1]=_z; acc[2]=_z; acc[3]=_z; }

// 64x64 NT MFMA tile: A (64 x K, row-major lda), B^T (64 x K, row-major ldb)
DEVI void gemm64(const f16* A, int lda, const f16* Bm, int ldb, int K,
                 f16* lA, f16* lB, f32x4 acc[4]){
  const int lane = threadIdx.x & 63, wv = threadIdx.x >> 6;
  const int l15 = lane & 15, kq = lane >> 4;
  for (int k0=0; k0<K; k0+=32){
    __syncthreads();
    stage_tile(A + k0, lda, lA);
    stage_tile(Bm + k0, ldb, lB);
    __syncthreads();
    f16x8 af = frag_ld(lA + (16*wv + l15)*LDT + kq*8);
    #pragma unroll
    for (int nt=0; nt<4; nt++){
      f16x8 bf = frag_ld(lB + (16*nt + l15)*LDT + kq*8);
      acc[nt] = __builtin_amdgcn_mfma_f32_16x16x32_f16(af, bf, acc[nt], 0,0,0);
    }
  }
}

// ---------------- small prep kernels ----------------
__global__ void k_cvt(const float* __restrict__ s, f16* __restrict__ d, int n){
  int i = blockIdx.x*256 + threadIdx.x;
  if (i < n) d[i] = (f16)s[i];
}
// gconv (K,Fi,Fo) -> gcT (Fo, K*Fi)
__global__ void k_gconvT(const float* __restrict__ s, f16* __restrict__ d){
  int id = blockIdx.x;            // k*256+fi : 1280
  int fo = threadIdx.x;           // 256
  d[(size_t)fo*1280 + id] = (f16)s[(size_t)id*256 + fo];
}
// gdecode (F,V) -> gdT (VP=2048, F) zero-padded rows
__global__ void k_gdecT(const float* __restrict__ s, f16* __restrict__ d){
  int v = blockIdx.x, f = threadIdx.x;    // 2048 x 256
  f16 val = (f16)0.f;
  if (v < 2000) val = (f16)s[(size_t)f*2000 + v];
  d[(size_t)v*256 + f] = val;
}
// e_pad[b][p][f] = p in [2,514) ? tanh(gembed[xs[b][p-2]][f]) : 0
__global__ void k_epad(const int* __restrict__ xs, const float* __restrict__ gemb, f16* __restrict__ epad){
  int id = blockIdx.x;            // b*516+p
  int f = threadIdx.x;
  int b = id / 516, p = id % 516;
  float v = 0.f;
  if (p >= 2 && p < 514){ int idx = xs[b*512 + p - 2]; v = tanh_c(gemb[(size_t)idx*256 + f]); }
  epad[(size_t)id*256 + f] = (f16)v;
}
// enc/dec embeddings with <P mask
__global__ void k_embx(const int* __restrict__ xs, const int* __restrict__ ys,
                       const float* __restrict__ eemb, const float* __restrict__ demb,
                       f16* __restrict__ xo, f16* __restrict__ yo){
  int id = blockIdx.x; int f = threadIdx.x;  // 2*32*512 blocks x 128
  bool dec = id >= 32*512; int id2 = dec ? id - 32*512 : id;
  int idx = dec ? ys[id2] : xs[id2];
  if (idx < 4) idx = 0;
  const float* src = (dec ? demb : eemb) + (size_t)idx*128;
  (dec ? yo : xo)[(size_t)id2*128 + f] = (f16)src[f];
}

// ---------------- LSTM weight prep (3 storage sections) ----------------
// Section A (MFMA): rows 0..447. Wave w owns rows [w*112, w*112+112) = 7 row-tiles x 8 k-tiles.
// Frag (w,t16,kt), lane l, elem j: Whh[w*112 + t16*16 + (l&15)][kt*32 + (l>>4)*8 + j]
// stored at Wmf[((w*7+t16)*8+kt)*64 + l]  (uint4 = f16x8)
__global__ void k_wprep_mf(const float* __restrict__ Whh, uint4* __restrict__ Wmf){
  const int bid = blockIdx.x;     // 224 = 4*7*8
  const int l = threadIdx.x;      // 64
  const int w = bid / 56, t16 = (bid / 8) % 7, kt = bid & 7;
  const int row = w*112 + t16*16 + (l & 15);
  const int kb  = kt*32 + (l >> 4)*8;
  f16 tmp[8];
  #pragma unroll
  for (int j=0;j<8;j++) tmp[j] = (f16)Whh[(size_t)row*256 + kb + j];
  Wmf[(size_t)bid*64 + l] = *(uint4*)tmp;
}
// Section B (VGPR dot2): rows 448..767. thread (c=tid&3, r=tid>>2): rows {448+r+64m, m=0..4},
// k-chunk [c*64, c*64+64). Wvg[k40=m*8+q][tid] holds Whh[448+r+64m][c*64 + q*8 .. +8)
__global__ void k_wprep_vg(const float* __restrict__ Whh, uint4* __restrict__ Wvg){
  const int k40 = blockIdx.x;     // 0..39
  const int tid = threadIdx.x;    // 256
  const int m = k40 >> 3, q = k40 & 7;
  const int row = 448 + (tid >> 2) + 64*m;
  const int kb  = (tid & 3)*64 + q*8;
  f16 tmp[8];
  #pragma unroll
  for (int j=0;j<8;j++) tmp[j] = (f16)Whh[(size_t)row*256 + kb + j];
  Wvg[(size_t)k40*256 + tid] = *(uint4*)tmp;
}
// Section C (LDS dot2): rows 768..1023. same scheme, m=0..3. Wld[j=m*8+q][tid]
__global__ void k_wprep_ld(const float* __restrict__ Whh, uint4* __restrict__ Wld){
  const int j32 = blockIdx.x;     // 0..31
  const int tid = threadIdx.x;    // 256
  const int m = j32 >> 3, q = j32 & 7;
  const int row = 768 + (tid >> 2) + 64*m;
  const int kb  = (tid & 3)*64 + q*8;
  f16 tmp[8];
  #pragma unroll
  for (int j=0;j<8;j++) tmp[j] = (f16)Whh[(size_t)row*256 + kb + j];
  Wld[(size_t)j32*256 + tid] = *(uint4*)tmp;
}

// ---------------- GEMM kernels ----------------
__global__ __launch_bounds__(256,4) void k_conv(const f16* __restrict__ epad, const f16* __restrict__ gcT, f16* __restrict__ tf){
  __shared__ f16 lA[64*LDT], lB[64*LDT];
  const int m0 = blockIdx.x*64, n0 = blockIdx.y*64;
  const int b = m0 >> 9, n = m0 & 511;
  f32x4 acc[4]; ZERO4(acc);
  gemm64(epad + ((size_t)b*516 + n)*256, 256, gcT + (size_t)n0*1280, 1280, 1280, lA, lB, acc);
  const int lane=threadIdx.x&63, wv=threadIdx.x>>6, l15=lane&15, kq=lane>>4;
  #pragma unroll
  for (int nt=0;nt<4;nt++)
    #pragma unroll
    for (int r=0;r<4;r++)
      tf[(size_t)(m0 + 16*wv + 4*kq + r)*256 + n0 + nt*16 + l15] = (f16)tanh_c(acc[nt][r]);
}

__global__ __launch_bounds__(256,4) void k_u(const f16* __restrict__ X, const f16* __restrict__ Wih,
                                             const float* __restrict__ bias, f16* __restrict__ U){
  __shared__ f16 lA[64*LDT], lB[64*LDT];
  const int m0 = blockIdx.x*64, n0 = blockIdx.y*64;
  f32x4 acc[4]; ZERO4(acc);
  gemm64(X + (size_t)m0*128, 128, Wih + (size_t)n0*128, 128, 128, lA, lB, acc);
  const int lane=threadIdx.x&63, wv=threadIdx.x>>6, l15=lane&15, kq=lane>>4;
  #pragma unroll
  for (int nt=0;nt<4;nt++){
    float bv = bias[n0 + nt*16 + l15];
    #pragma unroll
    for (int r=0;r<4;r++)
      U[(size_t)(m0 + 16*wv + 4*kq + r)*1024 + n0 + nt*16 + l15] = (f16)(acc[nt][r] + bv);
  }
}

__global__ __launch_bounds__(256,4) void k_th(const f16* __restrict__ henh, const f16* __restrict__ Tf, f16* __restrict__ Th){
  __shared__ f16 lA[64*LDT], lB[64*LDT];
  const int m0 = blockIdx.x*64, n0 = blockIdx.y*64;
  f32x4 acc[4]; ZERO4(acc);
  gemm64(henh + (size_t)m0*512, 512, Tf + (size_t)n0*512, 512, 512, lA, lB, acc);
  const int lane=threadIdx.x&63, wv=threadIdx.x>>6, l15=lane&15, kq=lane>>4;
  #pragma unroll
  for (int nt=0;nt<4;nt++)
    #pragma unroll
    for (int r=0;r<4;r++)
      Th[(size_t)(m0 + 16*wv + 4*kq + r)*256 + n0 + nt*16 + l15] = (f16)acc[nt][r];
}

// pass1: online row-max + sum-exp of logits = tf @ gdT^T over N=2048 (cols>=2000 masked)
__global__ __launch_bounds__(256,2) void k_pass1(const f16* __restrict__ tf, const f16* __restrict__ gdT,
                                                 float* __restrict__ mxp, float* __restrict__ sep){
  __shared__ f16 lA[64*LDA];
  __shared__ f16 lB[64*LDT];
  __shared__ float mx_s[64], se_s[64];
  const int mt = blockIdx.x, ns = blockIdx.y;
  const int tid = threadIdx.x, lane=tid&63, wv=tid>>6, l15=lane&15, kq=lane>>4;
  {
    const f16* A = tf + (size_t)mt*64*256;
    int row = tid>>2, qq = tid&3;
    #pragma unroll
    for (int c=0;c<8;c++)
      *(f16x8*)(lA + row*LDA + c*32 + qq*8) = *(const f16x8*)(A + (size_t)row*256 + c*32 + qq*8);
  }
  if (tid < 64){ mx_s[tid] = -1e30f; se_s[tid] = 0.f; }
  __syncthreads();
  for (int nc=0; nc<8; nc++){
    const int nbase = ns*512 + nc*64;
    const f16* Bm = gdT + (size_t)nbase*256;
    f32x4 acc[4]; ZERO4(acc);
    for (int k0=0; k0<256; k0+=32){
      __syncthreads();
      stage_tile(Bm + k0, 256, lB);
      __syncthreads();
      f16x8 af = frag_ld(lA + (16*wv + l15)*LDA + k0 + kq*8);
      #pragma unroll
      for (int nt=0; nt<4; nt++){
        f16x8 bf = frag_ld(lB + (16*nt + l15)*LDT + kq*8);
        acc[nt] = __builtin_amdgcn_mfma_f32_16x16x32_f16(af, bf, acc[nt], 0,0,0);
      }
    }
    #pragma unroll
    for (int r=0;r<4;r++){
      float av[4]; float cm = -1e30f;
      #pragma unroll
      for (int nt=0;nt<4;nt++){
        int gcol = nbase + nt*16 + l15;
        float a = (gcol < 2000) ? acc[nt][r] : -1e30f;
        av[nt] = a; cm = fmaxf(cm, a);
      }
      cm = wmax16(cm);
      int rr = 16*wv + 4*kq + r;
      float old = mx_s[rr];
      float nm = fmaxf(old, cm);
      float ss = 0.f;
      #pragma unroll
      for (int nt=0;nt<4;nt++) ss += __expf(av[nt] - nm);
      ss = wsum16(ss);
      if (l15 == 0){
        se_s[rr] = se_s[rr]*__expf(old - nm) + ss;
        mx_s[rr] = nm;
      }
    }
  }
  __syncthreads();
  if (tid < 64){
    mxp[(size_t)ns*16384 + mt*64 + tid] = mx_s[tid];
    sep[(size_t)ns*16384 + mt*64 + tid] = se_s[tid];
  }
}

__global__ void k_comb1(const float* __restrict__ mxp, const float* __restrict__ sep,
                        float* __restrict__ mx, float* __restrict__ se){
  int m = blockIdx.x*256 + threadIdx.x;
  float best = -1e30f;
  #pragma unroll
  for (int k=0;k<4;k++) best = fmaxf(best, mxp[(size_t)k*16384 + m]);
  float s = 0.f;
  #pragma unroll
  for (int k=0;k<4;k++) s += sep[(size_t)k*16384 + m] * __expf(mxp[(size_t)k*16384 + m] - best);
  mx[m] = best; se[m] = s;
}

// pass2: scoresT[b][j][i] = exp(logit(i, ys[b][j]) - mx)/se  via gathered-row GEMM
__global__ __launch_bounds__(256,4) void k_pass2(const f16* __restrict__ tf, const f16* __restrict__ gdT,
                                                 const int* __restrict__ ys, const float* __restrict__ mx,
                                                 const float* __restrict__ se, f16* __restrict__ scT){
  __shared__ f16 lA[64*LDT], lB[64*LDT];
  __shared__ int jv[64];
  const int it = blockIdx.x, jt = blockIdx.y, b = blockIdx.z;
  const int tid = threadIdx.x, lane=tid&63, wv=tid>>6, l15=lane&15, kq=lane>>4;
  if (tid<64) jv[tid] = ys[b*512 + jt*64 + tid];
  const f16* A = tf + ((size_t)b*512 + it*64)*256;
  f32x4 acc[4]; ZERO4(acc);
  for (int k0=0;k0<256;k0+=32){
    __syncthreads();
    stage_tile(A + k0, 256, lA);
    { int row=tid>>2, qq=tid&3;
      *(f16x8*)(lB + row*LDT + qq*8) = *(const f16x8*)(gdT + (size_t)jv[row]*256 + k0 + qq*8); }
    __syncthreads();
    f16x8 af = frag_ld(lA + (16*wv+l15)*LDT + kq*8);
    #pragma unroll
    for (int nt=0;nt<4;nt++){
      f16x8 bf = frag_ld(lB + (16*nt+l15)*LDT + kq*8);
      acc[nt] = __builtin_amdgcn_mfma_f32_16x16x32_f16(af, bf, acc[nt], 0,0,0);
    }
  }
  float mxv[4], rsev[4];
  #pragma unroll
  for (int r=0;r<4;r++){
    int i_ = it*64 + 16*wv + 4*kq + r;
    mxv[r] = mx[b*512 + i_];
    rsev[r] = 1.f / se[b*512 + i_];
  }
  #pragma unroll
  for (int nt=0;nt<4;nt++){
    int j_ = jt*64 + nt*16 + l15;
    #pragma unroll
    for (int r=0;r<4;r++){
      int i_ = it*64 + 16*wv + 4*kq + r;
      scT[((size_t)b*512 + j_)*512 + i_] = (f16)(__expf(acc[nt][r] - mxv[r]) * rsev[r]);
    }
  }
}

// fused eij -> softmax over i -> <scores,align> -> partials (i split in 2)
__global__ __launch_bounds__(256,2) void k_final(const f16* __restrict__ hdec, const f16* __restrict__ Th,
                                                 const f16* __restrict__ scT,
                                                 float* __restrict__ pmx, float* __restrict__ pden, float* __restrict__ pnum){
  __shared__ f16 lA[64*LDA];
  __shared__ f16 lB[64*LDT];
  __shared__ float mx_s[64], den_s[64], num_s[64];
  const int is = blockIdx.x, jt = blockIdx.y, b = blockIdx.z;
  const int tid = threadIdx.x, lane=tid&63, wv=tid>>6, l15=lane&15, kq=lane>>4;
  {
    const f16* A = hdec + ((size_t)b*512 + jt*64)*256;
    int row = tid>>2, qq = tid&3;
    #pragma unroll
    for (int c=0;c<8;c++)
      *(f16x8*)(lA + row*LDA + c*32 + qq*8) = *(const f16x8*)(A + (size_t)row*256 + c*32 + qq*8);
  }
  if (tid<64){ mx_s[tid]=-1e30f; den_s[tid]=0.f; num_s[tid]=0.f; }
  __syncthreads();
  for (int ic=0; ic<4; ic++){
    const int i0 = is*256 + ic*64;
    const f16* Bm = Th + ((size_t)b*512 + i0)*256;
    f32x4 acc[4]; ZERO4(acc);
    for (int k0=0;k0<256;k0+=32){
      __syncthreads();
      stage_tile(Bm + k0, 256, lB);
      __syncthreads();
      f16x8 af = frag_ld(lA + (16*wv+l15)*LDA + k0 + kq*8);
      #pragma unroll
      for (int nt=0;nt<4;nt++){
        f16x8 bf = frag_ld(lB + (16*nt+l15)*LDT + kq*8);
        acc[nt] = __builtin_amdgcn_mfma_f32_16x16x32_f16(af, bf, acc[nt], 0,0,0);
      }
    }
    #pragma unroll
    for (int r=0;r<4;r++){
      int jl = 16*wv + 4*kq + r;
      float av[4]; float cm=-1e30f;
      #pragma unroll
      for (int nt=0;nt<4;nt++){ av[nt]=acc[nt][r]; cm=fmaxf(cm,av[nt]); }
      cm = wmax16(cm);
      float old = mx_s[jl], nm = fmaxf(old, cm);
      float ds=0.f, nsum=0.f;
      const size_t srow = ((size_t)b*512 + jt*64 + jl)*512;
      #pragma unroll
      for (int nt=0;nt<4;nt++){
        float e = __expf(av[nt]-nm);
        float sc = (float)scT[srow + i0 + nt*16 + l15];
        ds += e; nsum += sc*e;
      }
      ds = wsum16(ds); nsum = wsum16(nsum);
      if (l15==0){
        float fac = __expf(old-nm);
        den_s[jl] = den_s[jl]*fac + ds;
        num_s[jl] = num_s[jl]*fac + nsum;
        mx_s[jl] = nm;
      }
    }
  }
  __syncthreads();
  if (tid<64){
    size_t idx = (((size_t)b*512) + jt*64 + tid)*2 + is;
    pmx[idx]=mx_s[tid]; pden[idx]=den_s[tid]; pnum[idx]=num_s[tid];
  }
}

__global__ void k_comb2(const float* __restrict__ pmx, const float* __restrict__ pden,
                        const float* __restrict__ pnum, float* __restrict__ out){
  const int b = blockIdx.x, j = threadIdx.x;    // 32 x 512
  size_t base = ((size_t)b*512 + j)*2;
  float m0=pmx[base], m1=pmx[base+1];
  float m = fmaxf(m0,m1);
  float e0=__expf(m0-m), e1=__expf(m1-m);
  float den = pden[base]*e0 + pden[base+1]*e1;
  float num = pnum[base]*e0 + pnum[base+1]*e1;
  float lp = __logf(num) - __logf(den);
  __shared__ float red[512];
  red[j] = lp;
  __syncthreads();
  for (int st=256; st>0; st>>=1){ if (j<st) red[j]+=red[j+st]; __syncthreads(); }
  if (j==0) atomicAdd(out, -red[0]);
}

// ---------------- LSTM v4: MFMA(AGPR 448 rows) + VGPR-dot2(320) + LDS-dot2(256) ----------------
// One WG (256 thr, 4 waves) per sequence. All z published to zl[1024] (LDS); each thread then
// owns hidden unit `tid` for the gate nonlinearity. 2 barriers/step.
__global__ __launch_bounds__(256,1) void k_lstm4(
    const u16* __restrict__ U, const uint4* __restrict__ Wmf,
    const uint4* __restrict__ Wvg, const uint4* __restrict__ Wld,
    u16* __restrict__ hout, float* __restrict__ hTcT,
    u16* __restrict__ hdec0, int nsteps, int mode)
{
  __shared__ uint4 wl[32*256];               // 128 KiB LDS-resident weights (rows 768..1023)
  __shared__ float zl[1024];                 // z scatter board
  __shared__ __align__(16) f16 h16[264];     // h(t)

  const int tid = threadIdx.x;
  const int lane = tid & 63, wv = tid >> 6;
  const int c = tid & 3, r = tid >> 2;
  int dir = 0, b = blockIdx.x;
  if (mode == 0){ dir = (b >= 32) ? 1 : 0; b &= 31; }

  // Section A: MFMA A-fragments (AGPR-resident; only read by MFMA)
  f16x8 amf[56];
  #pragma unroll
  for (int t=0;t<56;t++){
    uint4 v = Wmf[(size_t)(wv*56 + t)*64 + lane];
    amf[t] = __builtin_bit_cast(f16x8, v);
  }
  // Section B: VGPR weights
  uint4 wr[40];
  #pragma unroll
  for (int k=0;k<40;k++) wr[k] = Wvg[(size_t)k*256 + tid];
  // Section C: LDS weights
  #pragma unroll
  for (int j=0;j<32;j++) wl[j*256 + tid] = Wld[(size_t)j*256 + tid];

  float cst;
  if (mode == 0){
    h16[tid] = (f16)0.f; cst = 0.f;
  } else {
    h16[tid] = (f16)hTcT[(size_t)b*512 + tid];
    cst = hTcT[(size_t)b*512 + 256 + tid];
  }
  __syncthreads();

  #pragma unroll 1
  for (int t=0; t<nsteps; ++t){
    const int tpos = dir ? (nsteps-1-t) : t;
    const size_t ubase = ((size_t)b*512 + tpos)*1024;

    // U prefetch: 4 gate pre-activations for unit `tid`
    u16 uvv[4];
    #pragma unroll
    for (int g=0;g<4;g++) uvv[g] = U[ubase + g*256 + tid];

    // ---- Section A: MFMA, rows [wv*112, wv*112+112) ----
    // B-frag: h replicated over the 16 N-cols: elem j = h[kt*32 + (lane>>4)*8 + j]
    f16x8 bfr[8];
    #pragma unroll
    for (int kt=0;kt<8;kt++) bfr[kt] = frag_ld(h16 + kt*32 + (lane>>4)*8);
    #pragma unroll
    for (int t16=0;t16<7;t16++){
      f32x4 D = {0.f,0.f,0.f,0.f};
      #pragma unroll
      for (int kt=0;kt<8;kt++)
        D = __builtin_amdgcn_mfma_f32_16x16x32_f16(amf[t16*8+kt], bfr[kt], D, 0,0,0);
      if ((lane & 15) == 0)
        *(f32x4*)(zl + wv*112 + t16*16 + (lane>>4)*4) = D;   // cols identical; col-0 lanes publish
    }

    // ---- Sections B + C: dot2, k-chunk c, rows 448+r+64m (m<5) and 768+r+64m (m<4) ----
    float aB[5] = {0.f,0.f,0.f,0.f,0.f};
    float aC[4] = {0.f,0.f,0.f,0.f};
    #pragma unroll
    for (int q=0;q<8;q++){
      uint4 hq = *(const uint4*)(h16 + c*64 + q*8);
      #pragma unroll
      for (int m=0;m<5;m++){
        uint4 w4 = wr[m*8+q];
        aB[m] = dot2u(w4.x, hq.x, aB[m]);
        aB[m] = dot2u(w4.y, hq.y, aB[m]);
        aB[m] = dot2u(w4.z, hq.z, aB[m]);
        aB[m] = dot2u(w4.w, hq.w, aB[m]);
      }
      #pragma unroll
      for (int m=0;m<4;m++){
        uint4 w4 = wl[(m*8+q)*256 + tid];
        aC[m] = dot2u(w4.x, hq.x, aC[m]);
        aC[m] = dot2u(w4.y, hq.y, aC[m]);
        aC[m] = dot2u(w4.z, hq.z, aC[m]);
        aC[m] = dot2u(w4.w, hq.w, aC[m]);
      }
    }
    #pragma unroll
    for (int m=0;m<5;m++){ aB[m] += __shfl_xor(aB[m],1,64); aB[m] += __shfl_xor(aB[m],2,64); }
    #pragma unroll
    for (int m=0;m<4;m++){ aC[m] += __shfl_xor(aC[m],1,64); aC[m] += __shfl_xor(aC[m],2,64); }
    if (c == 0){
      #pragma unroll
      for (int m=0;m<5;m++) zl[448 + r + 64*m] = aB[m];
      #pragma unroll
      for (int m=0;m<4;m++) zl[768 + r + 64*m] = aC[m];
    }
    __syncthreads();   // zl complete; all h16 reads done

    // ---- epilogue: unit `tid` ----
    float zi = zl[tid]        + (float)__builtin_bit_cast(f16, uvv[0]);
    float zf = zl[256 + tid]  + (float)__builtin_bit_cast(f16, uvv[1]);
    float zg = zl[512 + tid]  + (float)__builtin_bit_cast(f16, uvv[2]);
    float zo = zl[768 + tid]  + (float)__builtin_bit_cast(f16, uvv[3]);
    cst = sigf(zf)*cst + sigf(zi)*tanh_c(zg);
    float h = sigf(zo)*tanh_c(cst);
    f16 hf = (f16)h;
    h16[tid] = hf;
    if (mode == 0){
      hout[((size_t)b*512 + tpos)*512 + dir*256 + tid] = __builtin_bit_cast(u16, hf);
      if (!dir && t == nsteps-1){
        hdec0[(size_t)b*512*256 + tid] = __builtin_bit_cast(u16, hf);
        hTcT[(size_t)b*512 + tid] = h;
        hTcT[(size_t)b*512 + 256 + tid] = cst;
      }
    } else {
      hout[((size_t)b*512 + (t+1))*256 + tid] = __builtin_bit_cast(u16, hf);
    }
    __syncthreads();   // h(t+1) visible
  }
}

// ---------------- host ----------------
extern "C" void kernel_launch(void* const* d_in, const int* in_sizes, int n_in,
                              void* d_out, int out_size, void* d_ws, size_t ws_size,
                              hipStream_t stream)
{
  (void)in_sizes; (void)n_in; (void)out_size;
  const int*   xs    = (const int*)d_in[0];
  const int*   ys    = (const int*)d_in[1];
  const float* gemb  = (const float*)d_in[2];
  const float* gconv = (const float*)d_in[3];
  const float* gdec  = (const float*)d_in[4];
  const float* eemb  = (const float*)d_in[5];
  const float* demb  = (const float*)d_in[6];
  const float* eWih  = (const float*)d_in[7];
  const float* eWhh  = (const float*)d_in[8];
  const float* eb    = (const float*)d_in[9];
  const float* dWih  = (const float*)d_in[10];
  const float* dWhh  = (const float*)d_in[11];
  const float* db    = (const float*)d_in[12];
  const float* Tm    = (const float*)d_in[13];

  char* wsb = (char*)d_ws;
  size_t off = 0;
  auto take = [&](size_t bytes)->char*{ char* p = wsb + off; off += (bytes + 255) & ~(size_t)255; return p; };
  f16* epad  = (f16*)take((size_t)32*516*256*2);
  f16* tf    = (f16*)take((size_t)32*512*256*2);
  f16* xemb  = (f16*)take((size_t)32*512*128*2);
  f16* yemb  = (f16*)take((size_t)32*512*128*2);
  f16* Uenc  = (f16*)take((size_t)32*512*1024*2);
  f16* Udec  = (f16*)take((size_t)32*512*1024*2);
  f16* henh  = (f16*)take((size_t)32*512*512*2);
  f16* hdec  = (f16*)take((size_t)32*512*256*2);
  f16* Th    = (f16*)take((size_t)32*512*256*2);
  f16* scT   = (f16*)take((size_t)32*512*512*2);
  float* mx  = (float*)take((size_t)16384*4);
  float* se  = (float*)take((size_t)16384*4);
  float* mxp = (float*)take((size_t)4*16384*4);
  float* sep = (float*)take((size_t)4*16384*4);
  float* pmx = (float*)take((size_t)32*512*2*4);
  float* pden= (float*)take((size_t)32*512*2*4);
  float* pnum= (float*)take((size_t)32*512*2*4);
  float* hTcT= (float*)take((size_t)32*512*4);
  f16* Wihe  = (f16*)take((size_t)1024*128*2);
  f16* Wihd  = (f16*)take((size_t)1024*128*2);
  f16* Tf    = (f16*)take((size_t)256*512*2);
  f16* gcT   = (f16*)take((size_t)256*1280*2);
  f16* gdT   = (f16*)take((size_t)2048*256*2);
  uint4* Wmfe = (uint4*)take((size_t)224*64*16);
  uint4* Wvge = (uint4*)take((size_t)40*256*16);
  uint4* Wlde = (uint4*)take((size_t)32*256*16);
  uint4* Wmfd = (uint4*)take((size_t)224*64*16);
  uint4* Wvgd = (uint4*)take((size_t)40*256*16);
  uint4* Wldd = (uint4*)take((size_t)32*256*16);
  if (off > ws_size) return;  // insufficient scratch -> visible as wrong answer

  hipMemsetAsync(d_out, 0, sizeof(float), stream);

  // weight conversions / splits
  k_cvt<<<dim3(512),  256, 0, stream>>>(eWih, Wihe, 1024*128);
  k_cvt<<<dim3(512),  256, 0, stream>>>(dWih, Wihd, 1024*128);
  k_cvt<<<dim3(512),  256, 0, stream>>>(Tm,   Tf,   256*512);
  k_gconvT<<<dim3(1280), 256, 0, stream>>>(gconv, gcT);
  k_gdecT <<<dim3(2048), 256, 0, stream>>>(gdec, gdT);
  k_wprep_mf<<<dim3(224), 64, 0, stream>>>(eWhh, Wmfe);
  k_wprep_vg<<<dim3(40), 256, 0, stream>>>(eWhh, Wvge);
  k_wprep_ld<<<dim3(32), 256, 0, stream>>>(eWhh, Wlde);
  k_wprep_mf<<<dim3(224), 64, 0, stream>>>(dWhh, Wmfd);
  k_wprep_vg<<<dim3(40), 256, 0, stream>>>(dWhh, Wvgd);
  k_wprep_ld<<<dim3(32), 256, 0, stream>>>(dWhh, Wldd);

  // embeddings
  k_epad<<<dim3(32*516), 256, 0, stream>>>(xs, gemb, epad);
  k_embx<<<dim3(2*32*512), 128, 0, stream>>>(xs, ys, eemb, demb, xemb, yemb);

  // G-stack
  k_conv<<<dim3(256,4), 256, 0, stream>>>(epad, gcT, tf);
  k_pass1<<<dim3(256,4), 256, 0, stream>>>(tf, gdT, mxp, sep);
  k_comb1<<<dim3(64), 256, 0, stream>>>(mxp, sep, mx, se);
  k_pass2<<<dim3(8,8,32), 256, 0, stream>>>(tf, gdT, ys, mx, se, scT);

  // LSTM input-gate precompute
  k_u<<<dim3(256,16), 256, 0, stream>>>(xemb, Wihe, eb, Uenc);
  k_u<<<dim3(256,16), 256, 0, stream>>>(yemb, Wihd, db, Udec);

  // recurrences
  k_lstm4<<<dim3(64), 256, 0, stream>>>((const u16*)Uenc, Wmfe, Wvge, Wlde, (u16*)henh, hTcT, (u16*)hdec, 512, 0);
  k_lstm4<<<dim3(32), 256, 0, stream>>>((const u16*)Udec, Wmfd, Wvgd, Wldd, (u16*)hdec, hTcT, (u16*)hdec, 511, 1);

  // alignment
  k_th<<<dim3(256,4), 256, 0, stream>>>(henh, Tf, Th);
  k_final<<<dim3(2,8,32), 256, 0, stream>>>(hdec, Th, scT, pmx, pden, pnum);
  k_comb2<<<dim3(32), 512, 0, stream>>>(pmx, pden, pnum, (float*)d_out);
}

// Round 5
// 1733.950 us; speedup vs baseline: 2.3127x; 1.9810x over previous
//
#include <hip/hip_runtime.h>

typedef _Float16 f16;
typedef _Float16 f16x2 __attribute__((ext_vector_type(2)));
typedef _Float16 f16x8 __attribute__((ext_vector_type(8)));
typedef float    f32x4 __attribute__((ext_vector_type(4)));
typedef int      i32x4 __attribute__((ext_vector_type(4)));
typedef unsigned int u32;
typedef unsigned short u16;

#define DEVI static __device__ __forceinline__

static constexpr int LDT = 40;    // lds row stride (halves) for 64x32 tiles (+8 pad)
static constexpr int LDA = 264;   // lds row stride for 64x256 resident A tiles

DEVI float sigf(float x){ return 1.f/(1.f + __expf(-x)); }
DEVI float tanh_c(float x){
  x = fminf(fmaxf(x, -15.f), 15.f);
  float e = __expf(2.f*x);
  return (e - 1.f)/(e + 1.f);
}
// fast variants for the LSTM hot loop (explicit v_rcp, no div sequence)
DEVI float sig_f(float x){ return __builtin_amdgcn_rcpf(1.f + __expf(-x)); }
DEVI float tanh_f(float x){ return 1.f - 2.f*__builtin_amdgcn_rcpf(1.f + __expf(2.f*x)); }
DEVI float wmax16(float v){
  #pragma unroll
  for (int m=1;m<16;m<<=1) v = fmaxf(v, __shfl_xor(v, m, 64));
  return v;
}
DEVI float wsum16(float v){
  #pragma unroll
  for (int m=1;m<16;m<<=1) v += __shfl_xor(v, m, 64);
  return v;
}
DEVI f16x8 frag_ld(const f16* p){ return *(const f16x8*)p; }
DEVI void stage_tile(const f16* src, int ld, f16* dst){
  int tid = threadIdx.x; int row = tid>>2, qq = tid&3;
  *(f16x8*)(dst + row*LDT + qq*8) = *(const f16x8*)(src + (size_t)row*ld + qq*8);
}
#define ZERO4(acc) { f32x4 _z = {0.f,0.f,0.f,0.f}; acc[0]=_z; acc[1]=_z; acc[2]=_z; acc[3]=_z; }

// 64x64 NT MFMA tile: A (64 x K, row-major lda), B^T (64 x K, row-major ldb)
DEVI void gemm64(const f16* A, int lda, const f16* Bm, int ldb, int K,
                 f16* lA, f16* lB, f32x4 acc[4]){
  const int lane = threadIdx.x & 63, wv = threadIdx.x >> 6;
  const int l15 = lane & 15, kq = lane >> 4;
  for (int k0=0; k0<K; k0+=32){
    __syncthreads();
    stage_tile(A + k0, lda, lA);
    stage_tile(Bm + k0, ldb, lB);
    __syncthreads();
    f16x8 af = frag_ld(lA + (16*wv + l15)*LDT + kq*8);
    #pragma unroll
    for (int nt=0; nt<4; nt++){
      f16x8 bf = frag_ld(lB + (16*nt + l15)*LDT + kq*8);
      acc[nt] = __builtin_amdgcn_mfma_f32_16x16x32_f16(af, bf, acc[nt], 0,0,0);
    }
  }
}

// ---------------- small prep kernels ----------------
__global__ void k_cvt(const float* __restrict__ s, f16* __restrict__ d, int n){
  int i = blockIdx.x*256 + threadIdx.x;
  if (i < n) d[i] = (f16)s[i];
}
__global__ void k_gconvT(const float* __restrict__ s, f16* __restrict__ d){
  int id = blockIdx.x;            // k*256+fi : 1280
  int fo = threadIdx.x;           // 256
  d[(size_t)fo*1280 + id] = (f16)s[(size_t)id*256 + fo];
}
__global__ void k_gdecT(const float* __restrict__ s, f16* __restrict__ d){
  int v = blockIdx.x, f = threadIdx.x;    // 2048 x 256
  f16 val = (f16)0.f;
  if (v < 2000) val = (f16)s[(size_t)f*2000 + v];
  d[(size_t)v*256 + f] = val;
}
__global__ void k_epad(const int* __restrict__ xs, const float* __restrict__ gemb, f16* __restrict__ epad){
  int id = blockIdx.x;            // b*516+p
  int f = threadIdx.x;
  int b = id / 516, p = id % 516;
  float v = 0.f;
  if (p >= 2 && p < 514){ int idx = xs[b*512 + p - 2]; v = tanh_c(gemb[(size_t)idx*256 + f]); }
  epad[(size_t)id*256 + f] = (f16)v;
}
__global__ void k_embx(const int* __restrict__ xs, const int* __restrict__ ys,
                       const float* __restrict__ eemb, const float* __restrict__ demb,
                       f16* __restrict__ xo, f16* __restrict__ yo){
  int id = blockIdx.x; int f = threadIdx.x;  // 2*32*512 blocks x 128
  bool dec = id >= 32*512; int id2 = dec ? id - 32*512 : id;
  int idx = dec ? ys[id2] : xs[id2];
  if (idx < 4) idx = 0;
  const float* src = (dec ? demb : eemb) + (size_t)idx*128;
  (dec ? yo : xo)[(size_t)id2*128 + f] = (f16)src[f];
}

// ---------------- LSTM i8 weight prep ----------------
// global absmax of Whh (1024x256 f32) -> ws[0] (u32 bits of positive float)
__global__ void k_wmax(const float* __restrict__ Whh, u32* __restrict__ ws){
  int i = (blockIdx.x*256 + threadIdx.x)*4;
  float m = 0.f;
  #pragma unroll
  for (int j=0;j<4;j++) m = fmaxf(m, fabsf(Whh[i+j]));
  #pragma unroll
  for (int d=1; d<64; d<<=1) m = fmaxf(m, __shfl_xor(m, d, 64));
  if ((threadIdx.x & 63) == 0) atomicMax(ws, __float_as_uint(m));
}
// quantize Whh into i8 MFMA A-fragments.
// frag id = w*64 + tile*4 + kt  (w=wave, tile=g*4+uh, kt = K-tile of 64)
// lane l: row = g*256 + w*64 + uh*16 + (l&15); k = kt*64 + (l>>4)*16 + j (j=0..15)
__global__ void k_wq8(const float* __restrict__ Whh, const u32* __restrict__ ws,
                      i32x4* __restrict__ Wq){
  const int bid = blockIdx.x;     // 0..255
  const int l = threadIdx.x;      // 0..63
  const int w = bid >> 6, tile = (bid >> 2) & 15, kt = bid & 3;
  const int g = tile >> 2, uh = tile & 3;
  const int row = g*256 + w*64 + uh*16 + (l & 15);
  const int k0  = kt*64 + (l >> 4)*16;
  const float scale = 127.f / __uint_as_float(ws[0]);
  int dw[4];
  #pragma unroll
  for (int d=0; d<4; d++){
    u32 acc = 0;
    #pragma unroll
    for (int j=0; j<4; j++){
      float q = __builtin_rintf(Whh[(size_t)row*256 + k0 + d*4 + j] * scale);
      int qi = (int)fminf(fmaxf(q, -127.f), 127.f);
      acc |= ((u32)qi & 0xffu) << (8*j);
    }
    dw[d] = (int)acc;
  }
  i32x4 v = { dw[0], dw[1], dw[2], dw[3] };
  Wq[(size_t)bid*64 + l] = v;
}

// ---------------- GEMM kernels ----------------
__global__ __launch_bounds__(256,4) void k_conv(const f16* __restrict__ epad, const f16* __restrict__ gcT, f16* __restrict__ tf){
  __shared__ f16 lA[64*LDT], lB[64*LDT];
  const int m0 = blockIdx.x*64, n0 = blockIdx.y*64;
  const int b = m0 >> 9, n = m0 & 511;
  f32x4 acc[4]; ZERO4(acc);
  gemm64(epad + ((size_t)b*516 + n)*256, 256, gcT + (size_t)n0*1280, 1280, 1280, lA, lB, acc);
  const int lane=threadIdx.x&63, wv=threadIdx.x>>6, l15=lane&15, kq=lane>>4;
  #pragma unroll
  for (int nt=0;nt<4;nt++)
    #pragma unroll
    for (int r=0;r<4;r++)
      tf[(size_t)(m0 + 16*wv + 4*kq + r)*256 + n0 + nt*16 + l15] = (f16)tanh_c(acc[nt][r]);
}

__global__ __launch_bounds__(256,4) void k_u(const f16* __restrict__ X, const f16* __restrict__ Wih,
                                             const float* __restrict__ bias, f16* __restrict__ U){
  __shared__ f16 lA[64*LDT], lB[64*LDT];
  const int m0 = blockIdx.x*64, n0 = blockIdx.y*64;
  f32x4 acc[4]; ZERO4(acc);
  gemm64(X + (size_t)m0*128, 128, Wih + (size_t)n0*128, 128, 128, lA, lB, acc);
  const int lane=threadIdx.x&63, wv=threadIdx.x>>6, l15=lane&15, kq=lane>>4;
  #pragma unroll
  for (int nt=0;nt<4;nt++){
    float bv = bias[n0 + nt*16 + l15];
    #pragma unroll
    for (int r=0;r<4;r++)
      U[(size_t)(m0 + 16*wv + 4*kq + r)*1024 + n0 + nt*16 + l15] = (f16)(acc[nt][r] + bv);
  }
}

__global__ __launch_bounds__(256,4) void k_th(const f16* __restrict__ henh, const f16* __restrict__ Tf, f16* __restrict__ Th){
  __shared__ f16 lA[64*LDT], lB[64*LDT];
  const int m0 = blockIdx.x*64, n0 = blockIdx.y*64;
  f32x4 acc[4]; ZERO4(acc);
  gemm64(henh + (size_t)m0*512, 512, Tf + (size_t)n0*512, 512, 512, lA, lB, acc);
  const int lane=threadIdx.x&63, wv=threadIdx.x>>6, l15=lane&15, kq=lane>>4;
  #pragma unroll
  for (int nt=0;nt<4;nt++)
    #pragma unroll
    for (int r=0;r<4;r++)
      Th[(size_t)(m0 + 16*wv + 4*kq + r)*256 + n0 + nt*16 + l15] = (f16)acc[nt][r];
}

__global__ __launch_bounds__(256,2) void k_pass1(const f16* __restrict__ tf, const f16* __restrict__ gdT,
                                                 float* __restrict__ mxp, float* __restrict__ sep){
  __shared__ f16 lA[64*LDA];
  __shared__ f16 lB[64*LDT];
  __shared__ float mx_s[64], se_s[64];
  const int mt = blockIdx.x, ns = blockIdx.y;
  const int tid = threadIdx.x, lane=tid&63, wv=tid>>6, l15=lane&15, kq=lane>>4;
  {
    const f16* A = tf + (size_t)mt*64*256;
    int row = tid>>2, qq = tid&3;
    #pragma unroll
    for (int c=0;c<8;c++)
      *(f16x8*)(lA + row*LDA + c*32 + qq*8) = *(const f16x8*)(A + (size_t)row*256 + c*32 + qq*8);
  }
  if (tid < 64){ mx_s[tid] = -1e30f; se_s[tid] = 0.f; }
  __syncthreads();
  for (int nc=0; nc<8; nc++){
    const int nbase = ns*512 + nc*64;
    const f16* Bm = gdT + (size_t)nbase*256;
    f32x4 acc[4]; ZERO4(acc);
    for (int k0=0; k0<256; k0+=32){
      __syncthreads();
      stage_tile(Bm + k0, 256, lB);
      __syncthreads();
      f16x8 af = frag_ld(lA + (16*wv + l15)*LDA + k0 + kq*8);
      #pragma unroll
      for (int nt=0; nt<4; nt++){
        f16x8 bf = frag_ld(lB + (16*nt + l15)*LDT + kq*8);
        acc[nt] = __builtin_amdgcn_mfma_f32_16x16x32_f16(af, bf, acc[nt], 0,0,0);
      }
    }
    #pragma unroll
    for (int r=0;r<4;r++){
      float av[4]; float cm = -1e30f;
      #pragma unroll
      for (int nt=0;nt<4;nt++){
        int gcol = nbase + nt*16 + l15;
        float a = (gcol < 2000) ? acc[nt][r] : -1e30f;
        av[nt] = a; cm = fmaxf(cm, a);
      }
      cm = wmax16(cm);
      int rr = 16*wv + 4*kq + r;
      float old = mx_s[rr];
      float nm = fmaxf(old, cm);
      float ss = 0.f;
      #pragma unroll
      for (int nt=0;nt<4;nt++) ss += __expf(av[nt] - nm);
      ss = wsum16(ss);
      if (l15 == 0){
        se_s[rr] = se_s[rr]*__expf(old - nm) + ss;
        mx_s[rr] = nm;
      }
    }
  }
  __syncthreads();
  if (tid < 64){
    mxp[(size_t)ns*16384 + mt*64 + tid] = mx_s[tid];
    sep[(size_t)ns*16384 + mt*64 + tid] = se_s[tid];
  }
}

__global__ void k_comb1(const float* __restrict__ mxp, const float* __restrict__ sep,
                        float* __restrict__ mx, float* __restrict__ se){
  int m = blockIdx.x*256 + threadIdx.x;
  float best = -1e30f;
  #pragma unroll
  for (int k=0;k<4;k++) best = fmaxf(best, mxp[(size_t)k*16384 + m]);
  float s = 0.f;
  #pragma unroll
  for (int k=0;k<4;k++) s += sep[(size_t)k*16384 + m] * __expf(mxp[(size_t)k*16384 + m] - best);
  mx[m] = best; se[m] = s;
}

__global__ __launch_bounds__(256,4) void k_pass2(const f16* __restrict__ tf, const f16* __restrict__ gdT,
                                                 const int* __restrict__ ys, const float* __restrict__ mx,
                                                 const float* __restrict__ se, f16* __restrict__ scT){
  __shared__ f16 lA[64*LDT], lB[64*LDT];
  __shared__ int jv[64];
  const int it = blockIdx.x, jt = blockIdx.y, b = blockIdx.z;
  const int tid = threadIdx.x, lane=tid&63, wv=tid>>6, l15=lane&15, kq=lane>>4;
  if (tid<64) jv[tid] = ys[b*512 + jt*64 + tid];
  const f16* A = tf + ((size_t)b*512 + it*64)*256;
  f32x4 acc[4]; ZERO4(acc);
  for (int k0=0;k0<256;k0+=32){
    __syncthreads();
    stage_tile(A + k0, 256, lA);
    { int row=tid>>2, qq=tid&3;
      *(f16x8*)(lB + row*LDT + qq*8) = *(const f16x8*)(gdT + (size_t)jv[row]*256 + k0 + qq*8); }
    __syncthreads();
    f16x8 af = frag_ld(lA + (16*wv+l15)*LDT + kq*8);
    #pragma unroll
    for (int nt=0;nt<4;nt++){
      f16x8 bf = frag_ld(lB + (16*nt+l15)*LDT + kq*8);
      acc[nt] = __builtin_amdgcn_mfma_f32_16x16x32_f16(af, bf, acc[nt], 0,0,0);
    }
  }
  float mxv[4], rsev[4];
  #pragma unroll
  for (int r=0;r<4;r++){
    int i_ = it*64 + 16*wv + 4*kq + r;
    mxv[r] = mx[b*512 + i_];
    rsev[r] = 1.f / se[b*512 + i_];
  }
  #pragma unroll
  for (int nt=0;nt<4;nt++){
    int j_ = jt*64 + nt*16 + l15;
    #pragma unroll
    for (int r=0;r<4;r++){
      int i_ = it*64 + 16*wv + 4*kq + r;
      scT[((size_t)b*512 + j_)*512 + i_] = (f16)(__expf(acc[nt][r] - mxv[r]) * rsev[r]);
    }
  }
}

__global__ __launch_bounds__(256,2) void k_final(const f16* __restrict__ hdec, const f16* __restrict__ Th,
                                                 const f16* __restrict__ scT,
                                                 float* __restrict__ pmx, float* __restrict__ pden, float* __restrict__ pnum){
  __shared__ f16 lA[64*LDA];
  __shared__ f16 lB[64*LDT];
  __shared__ float mx_s[64], den_s[64], num_s[64];
  const int is = blockIdx.x, jt = blockIdx.y, b = blockIdx.z;
  const int tid = threadIdx.x, lane=tid&63, wv=tid>>6, l15=lane&15, kq=lane>>4;
  {
    const f16* A = hdec + ((size_t)b*512 + jt*64)*256;
    int row = tid>>2, qq = tid&3;
    #pragma unroll
    for (int c=0;c<8;c++)
      *(f16x8*)(lA + row*LDA + c*32 + qq*8) = *(const f16x8*)(A + (size_t)row*256 + c*32 + qq*8);
  }
  if (tid<64){ mx_s[tid]=-1e30f; den_s[tid]=0.f; num_s[tid]=0.f; }
  __syncthreads();
  for (int ic=0; ic<4; ic++){
    const int i0 = is*256 + ic*64;
    const f16* Bm = Th + ((size_t)b*512 + i0)*256;
    f32x4 acc[4]; ZERO4(acc);
    for (int k0=0;k0<256;k0+=32){
      __syncthreads();
      stage_tile(Bm + k0, 256, lB);
      __syncthreads();
      f16x8 af = frag_ld(lA + (16*wv+l15)*LDA + k0 + kq*8);
      #pragma unroll
      for (int nt=0;nt<4;nt++){
        f16x8 bf = frag_ld(lB + (16*nt+l15)*LDT + kq*8);
        acc[nt] = __builtin_amdgcn_mfma_f32_16x16x32_f16(af, bf, acc[nt], 0,0,0);
      }
    }
    #pragma unroll
    for (int r=0;r<4;r++){
      int jl = 16*wv + 4*kq + r;
      float av[4]; float cm=-1e30f;
      #pragma unroll
      for (int nt=0;nt<4;nt++){ av[nt]=acc[nt][r]; cm=fmaxf(cm,av[nt]); }
      cm = wmax16(cm);
      float old = mx_s[jl], nm = fmaxf(old, cm);
      float ds=0.f, nsum=0.f;
      const size_t srow = ((size_t)b*512 + jt*64 + jl)*512;
      #pragma unroll
      for (int nt=0;nt<4;nt++){
        float e = __expf(av[nt]-nm);
        float sc = (float)scT[srow + i0 + nt*16 + l15];
        ds += e; nsum += sc*e;
      }
      ds = wsum16(ds); nsum = wsum16(nsum);
      if (l15==0){
        float fac = __expf(old-nm);
        den_s[jl] = den_s[jl]*fac + ds;
        num_s[jl] = num_s[jl]*fac + nsum;
        mx_s[jl] = nm;
      }
    }
  }
  __syncthreads();
  if (tid<64){
    size_t idx = (((size_t)b*512) + jt*64 + tid)*2 + is;
    pmx[idx]=mx_s[tid]; pden[idx]=den_s[tid]; pnum[idx]=num_s[tid];
  }
}

__global__ void k_comb2(const float* __restrict__ pmx, const float* __restrict__ pden,
                        const float* __restrict__ pnum, float* __restrict__ out){
  const int b = blockIdx.x, j = threadIdx.x;    // 32 x 512
  size_t base = ((size_t)b*512 + j)*2;
  float m0=pmx[base], m1=pmx[base+1];
  float m = fmaxf(m0,m1);
  float e0=__expf(m0-m), e1=__expf(m1-m);
  float den = pden[base]*e0 + pden[base+1]*e1;
  float num = pnum[base]*e0 + pnum[base+1]*e1;
  float lp = __logf(num) - __logf(den);
  __shared__ float red[512];
  red[j] = lp;
  __syncthreads();
  for (int st=256; st>0; st>>=1){ if (j<st) red[j]+=red[j+st]; __syncthreads(); }
  if (j==0) atomicAdd(out, -red[0]);
}

// ---------------- LSTM v5: batched S=4 seqs/WG, i8 MFMA, Whh fully in AGPRs ----------------
// 256 thr (4 waves). Wave w owns rows {g*256 + w*64 + uh*16 + (0..16)} for all g,uh -> 64 i8
// A-frags (K=64 each) = 256 AGPRs. B cols replicated: col n = seq n&3, so each lane's D col
// is its own seq. Thread (lane): p=(l&15)>>2 selects its uh-tile; owns units
// ubase..ubase+3 (ubase = w*64+p*16+kq*4) of seq s=(l&15)&3. U double-buffer-staged via LDS.
// One __syncthreads per step.
__global__ __launch_bounds__(256,1) void k_lstm5(
    const f16* __restrict__ U, const i32x4* __restrict__ Wq, const u32* __restrict__ ws,
    u16* __restrict__ hout, float* __restrict__ hTcT,
    u16* __restrict__ hdec0, int nsteps, int mode)
{
  __shared__ __align__(16) f16 Ub[2][4*1032];     // staged U, stride 1032 (bank spread)
  __shared__ __align__(16) char h8[2][4*272];     // quantized h, stride 272

  const int tid = threadIdx.x;
  const int lane = tid & 63, wv = tid >> 6;
  const int l15 = lane & 15, kq = lane >> 4;
  const int p = l15 >> 2, s = l15 & 3;
  const int ubase = wv*64 + p*16 + kq*4;

  int dir = 0, b0;
  if (mode == 0){ dir = blockIdx.x >> 3; b0 = (blockIdx.x & 7)*4; }
  else b0 = blockIdx.x*4;

  const float zscale = __uint_as_float(ws[0]) * (1.f/(127.f*127.f));

  // A-fragments (MFMA-only use -> AGPR)
  i32x4 aw[64];
  #pragma unroll
  for (int f=0; f<64; f++) aw[f] = Wq[(size_t)(wv*64 + f)*64 + lane];

  // init h / c
  float cst[4];
  if (mode == 0){
    #pragma unroll
    for (int r=0;r<4;r++) cst[r] = 0.f;
    for (int i = tid; i < 544; i += 256) ((u32*)h8)[i] = 0u;
  } else {
    const float* hp = hTcT + (size_t)(b0+s)*512;
    float4 hv = *(const float4*)(hp + ubase);
    float4 cv = *(const float4*)(hp + 256 + ubase);
    cst[0]=cv.x; cst[1]=cv.y; cst[2]=cv.z; cst[3]=cv.w;
    float hvv[4] = {hv.x, hv.y, hv.z, hv.w};
    u32 pk = 0;
    #pragma unroll
    for (int r=0;r<4;r++){
      int q = (int)__builtin_rintf(hvv[r]*127.f);
      pk |= ((u32)q & 0xffu) << (8*r);
    }
    *(u32*)&h8[0][s*272 + ubase] = pk;
  }

  // stage U for step 0
  const int s_st = tid >> 6, col = (tid & 63)*16;
  {
    int tp0 = dir ? (nsteps-1) : 0;
    const int4* up = (const int4*)(U + ((size_t)(b0+s_st)*512 + tp0)*1024 + col);
    *(int4*)&Ub[0][s_st*1032 + col] = up[0];
    *(int4*)&Ub[0][s_st*1032 + col + 8] = up[1];
  }
  __syncthreads();

  int cur = 0;
  #pragma unroll 1
  for (int t=0; t<nsteps; ++t){
    const int tpos = dir ? (nsteps-1-t) : t;

    // prefetch next-step U (global, consumed at loop bottom)
    int tn = dir ? max(nsteps-2-t, 0) : min(t+1, nsteps-1);
    const int4* upn = (const int4*)(U + ((size_t)(b0+s_st)*512 + tn)*1024 + col);
    int4 pu0 = upn[0], pu1 = upn[1];

    // B-fragments: col n -> seq n&3 (replicated columns)
    i32x4 bf[4];
    #pragma unroll
    for (int kt=0; kt<4; kt++)
      bf[kt] = *(const i32x4*)&h8[cur][s*272 + kt*64 + kq*16];

    // MFMA: 16 tiles x 4 K-chunks
    i32x4 acc[16];
    #pragma unroll
    for (int tile=0; tile<16; tile++){
      i32x4 d = {0,0,0,0};
      #pragma unroll
      for (int kt=0; kt<4; kt++)
        d = __builtin_amdgcn_mfma_i32_16x16x64_i8(aw[tile*4+kt], bf[kt], d, 0,0,0);
      acc[tile] = d;
    }

    // own U pre-activations (4 gates x 4 units)
    int2 uvg[4];
    #pragma unroll
    for (int g=0; g<4; g++)
      uvg[g] = *(const int2*)&Ub[cur][s*1032 + g*256 + ubase];

    // epilogue: units ubase+r, seq s
    float hv[4];
    #pragma unroll
    for (int r=0; r<4; r++){
      float z[4];
      #pragma unroll
      for (int g=0; g<4; g++){
        int a01 = (p & 1) ? acc[g*4+1][r] : acc[g*4+0][r];
        int a23 = (p & 1) ? acc[g*4+3][r] : acc[g*4+2][r];
        int av  = (p & 2) ? a23 : a01;
        const f16* uptr = (const f16*)&uvg[g];
        z[g] = fmaf((float)av, zscale, (float)uptr[r]);
      }
      float ig = sig_f(z[0]);
      float fg = sig_f(z[1]);
      float gg = tanh_f(z[2]);
      float og = sig_f(z[3]);
      cst[r] = fg*cst[r] + ig*gg;
      hv[r] = og*tanh_f(cst[r]);
    }

    // pack h -> i8 (LDS, next buffer) and f16 (global)
    u32 pk = 0; u32 hf01, hf23;
    {
      u16 hb[4];
      #pragma unroll
      for (int r=0;r<4;r++){
        int q = (int)__builtin_rintf(hv[r]*127.f);
        pk |= ((u32)q & 0xffu) << (8*r);
        f16 hf = (f16)hv[r];
        hb[r] = __builtin_bit_cast(u16, hf);
      }
      hf01 = (u32)hb[0] | ((u32)hb[1] << 16);
      hf23 = (u32)hb[2] | ((u32)hb[3] << 16);
    }
    const int nxt = cur ^ 1;
    *(u32*)&h8[nxt][s*272 + ubase] = pk;
    // stage prefetched U into next buffer
    *(int4*)&Ub[nxt][s_st*1032 + col] = pu0;
    *(int4*)&Ub[nxt][s_st*1032 + col + 8] = pu1;

    if (mode == 0){
      int2 hh = { (int)hf01, (int)hf23 };
      *(int2*)(hout + ((size_t)(b0+s)*512 + tpos)*512 + dir*256 + ubase) = hh;
      if (!dir && t == nsteps-1){
        *(int2*)(hdec0 + (size_t)(b0+s)*512*256 + ubase) = hh;
        float* hp = hTcT + (size_t)(b0+s)*512;
        *(float4*)(hp + ubase) = make_float4(hv[0], hv[1], hv[2], hv[3]);
        *(float4*)(hp + 256 + ubase) = make_float4(cst[0], cst[1], cst[2], cst[3]);
      }
    } else {
      int2 hh = { (int)hf01, (int)hf23 };
      *(int2*)(hout + ((size_t)(b0+s)*512 + (t+1))*256 + ubase) = hh;
    }
    __syncthreads();
    cur = nxt;
  }
}

// ---------------- host ----------------
extern "C" void kernel_launch(void* const* d_in, const int* in_sizes, int n_in,
                              void* d_out, int out_size, void* d_ws, size_t ws_size,
                              hipStream_t stream)
{
  (void)in_sizes; (void)n_in; (void)out_size;
  const int*   xs    = (const int*)d_in[0];
  const int*   ys    = (const int*)d_in[1];
  const float* gemb  = (const float*)d_in[2];
  const float* gconv = (const float*)d_in[3];
  const float* gdec  = (const float*)d_in[4];
  const float* eemb  = (const float*)d_in[5];
  const float* demb  = (const float*)d_in[6];
  const float* eWih  = (const float*)d_in[7];
  const float* eWhh  = (const float*)d_in[8];
  const float* eb    = (const float*)d_in[9];
  const float* dWih  = (const float*)d_in[10];
  const float* dWhh  = (const float*)d_in[11];
  const float* db    = (const float*)d_in[12];
  const float* Tm    = (const float*)d_in[13];

  char* wsb = (char*)d_ws;
  size_t off = 0;
  auto take = [&](size_t bytes)->char*{ char* p = wsb + off; off += (bytes + 255) & ~(size_t)255; return p; };
  f16* epad  = (f16*)take((size_t)32*516*256*2);
  f16* tf    = (f16*)take((size_t)32*512*256*2);
  f16* xemb  = (f16*)take((size_t)32*512*128*2);
  f16* yemb  = (f16*)take((size_t)32*512*128*2);
  f16* Uenc  = (f16*)take((size_t)32*512*1024*2);
  f16* Udec  = (f16*)take((size_t)32*512*1024*2);
  f16* henh  = (f16*)take((size_t)32*512*512*2);
  f16* hdec  = (f16*)take((size_t)32*512*256*2);
  f16* Th    = (f16*)take((size_t)32*512*256*2);
  f16* scT   = (f16*)take((size_t)32*512*512*2);
  float* mx  = (float*)take((size_t)16384*4);
  float* se  = (float*)take((size_t)16384*4);
  float* mxp = (float*)take((size_t)4*16384*4);
  float* sep = (float*)take((size_t)4*16384*4);
  float* pmx = (float*)take((size_t)32*512*2*4);
  float* pden= (float*)take((size_t)32*512*2*4);
  float* pnum= (float*)take((size_t)32*512*2*4);
  float* hTcT= (float*)take((size_t)32*512*4);
  f16* Wihe  = (f16*)take((size_t)1024*128*2);
  f16* Wihd  = (f16*)take((size_t)1024*128*2);
  f16* Tf    = (f16*)take((size_t)256*512*2);
  f16* gcT   = (f16*)take((size_t)256*1280*2);
  f16* gdT   = (f16*)take((size_t)2048*256*2);
  i32x4* Wq8e = (i32x4*)take((size_t)256*64*16);
  i32x4* Wq8d = (i32x4*)take((size_t)256*64*16);
  u32* wsc   = (u32*)take(8);
  if (off > ws_size) return;  // insufficient scratch -> visible as wrong answer

  hipMemsetAsync(d_out, 0, sizeof(float), stream);
  hipMemsetAsync(wsc, 0, 8, stream);

  // weight conversions / quantization
  k_cvt<<<dim3(512),  256, 0, stream>>>(eWih, Wihe, 1024*128);
  k_cvt<<<dim3(512),  256, 0, stream>>>(dWih, Wihd, 1024*128);
  k_cvt<<<dim3(512),  256, 0, stream>>>(Tm,   Tf,   256*512);
  k_gconvT<<<dim3(1280), 256, 0, stream>>>(gconv, gcT);
  k_gdecT <<<dim3(2048), 256, 0, stream>>>(gdec, gdT);
  k_wmax<<<dim3(256), 256, 0, stream>>>(eWhh, wsc + 0);
  k_wmax<<<dim3(256), 256, 0, stream>>>(dWhh, wsc + 1);
  k_wq8<<<dim3(256), 64, 0, stream>>>(eWhh, wsc + 0, Wq8e);
  k_wq8<<<dim3(256), 64, 0, stream>>>(dWhh, wsc + 1, Wq8d);

  // embeddings
  k_epad<<<dim3(32*516), 256, 0, stream>>>(xs, gemb, epad);
  k_embx<<<dim3(2*32*512), 128, 0, stream>>>(xs, ys, eemb, demb, xemb, yemb);

  // G-stack
  k_conv<<<dim3(256,4), 256, 0, stream>>>(epad, gcT, tf);
  k_pass1<<<dim3(256,4), 256, 0, stream>>>(tf, gdT, mxp, sep);
  k_comb1<<<dim3(64), 256, 0, stream>>>(mxp, sep, mx, se);
  k_pass2<<<dim3(8,8,32), 256, 0, stream>>>(tf, gdT, ys, mx, se, scT);

  // LSTM input-gate precompute
  k_u<<<dim3(256,16), 256, 0, stream>>>(xemb, Wihe, eb, Uenc);
  k_u<<<dim3(256,16), 256, 0, stream>>>(yemb, Wihd, db, Udec);

  // recurrences: 16 WGs enc (8 fwd + 8 bwd quads), 8 WGs dec
  k_lstm5<<<dim3(16), 256, 0, stream>>>(Uenc, Wq8e, wsc + 0, (u16*)henh, hTcT, (u16*)hdec, 512, 0);
  k_lstm5<<<dim3(8),  256, 0, stream>>>(Udec, Wq8d, wsc + 1, (u16*)hdec, hTcT, (u16*)hdec, 511, 1);

  // alignment
  k_th<<<dim3(256,4), 256, 0, stream>>>(henh, Tf, Th);
  k_final<<<dim3(2,8,32), 256, 0, stream>>>(hdec, Th, scT, pmx, pden, pnum);
  k_comb2<<<dim3(32), 512, 0, stream>>>(pmx, pden, pnum, (float*)d_out);
}

// Round 6
// 1665.374 us; speedup vs baseline: 2.4079x; 1.0412x over previous
//
#include <hip/hip_runtime.h>

typedef _Float16 f16;
typedef _Float16 f16x2 __attribute__((ext_vector_type(2)));
typedef _Float16 f16x8 __attribute__((ext_vector_type(8)));
typedef float    f32x4 __attribute__((ext_vector_type(4)));
typedef int      i32x4 __attribute__((ext_vector_type(4)));
typedef unsigned int u32;
typedef unsigned short u16;

#define DEVI static __device__ __forceinline__

static constexpr int LDT = 40;    // lds row stride (halves) for 64x32 tiles (+8 pad)
static constexpr int LDA = 264;   // lds row stride for 64x256 resident A tiles

DEVI float sigf(float x){ return 1.f/(1.f + __expf(-x)); }
DEVI float tanh_c(float x){
  x = fminf(fmaxf(x, -15.f), 15.f);
  float e = __expf(2.f*x);
  return (e - 1.f)/(e + 1.f);
}
// fast variants for the LSTM hot loop (explicit v_rcp, no div sequence)
DEVI float sig_f(float x){ return __builtin_amdgcn_rcpf(1.f + __expf(-x)); }
DEVI float tanh_f(float x){ return 1.f - 2.f*__builtin_amdgcn_rcpf(1.f + __expf(2.f*x)); }
DEVI float wmax16(float v){
  #pragma unroll
  for (int m=1;m<16;m<<=1) v = fmaxf(v, __shfl_xor(v, m, 64));
  return v;
}
DEVI float wsum16(float v){
  #pragma unroll
  for (int m=1;m<16;m<<=1) v += __shfl_xor(v, m, 64);
  return v;
}
DEVI f16x8 frag_ld(const f16* p){ return *(const f16x8*)p; }
DEVI void stage_tile(const f16* src, int ld, f16* dst){
  int tid = threadIdx.x; int row = tid>>2, qq = tid&3;
  *(f16x8*)(dst + row*LDT + qq*8) = *(const f16x8*)(src + (size_t)row*ld + qq*8);
}
#define ZERO4(acc) { f32x4 _z = {0.f,0.f,0.f,0.f}; acc[0]=_z; acc[1]=_z; acc[2]=_z; acc[3]=_z; }

// 64x64 NT MFMA tile: A (64 x K, row-major lda), B^T (64 x K, row-major ldb)
DEVI void gemm64(const f16* A, int lda, const f16* Bm, int ldb, int K,
                 f16* lA, f16* lB, f32x4 acc[4]){
  const int lane = threadIdx.x & 63, wv = threadIdx.x >> 6;
  const int l15 = lane & 15, kq = lane >> 4;
  for (int k0=0; k0<K; k0+=32){
    __syncthreads();
    stage_tile(A + k0, lda, lA);
    stage_tile(Bm + k0, ldb, lB);
    __syncthreads();
    f16x8 af = frag_ld(lA + (16*wv + l15)*LDT + kq*8);
    #pragma unroll
    for (int nt=0; nt<4; nt++){
      f16x8 bf = frag_ld(lB + (16*nt + l15)*LDT + kq*8);
      acc[nt] = __builtin_amdgcn_mfma_f32_16x16x32_f16(af, bf, acc[nt], 0,0,0);
    }
  }
}

// ---------------- small prep kernels ----------------
__global__ void k_cvt(const float* __restrict__ s, f16* __restrict__ d, int n){
  int i = blockIdx.x*256 + threadIdx.x;
  if (i < n) d[i] = (f16)s[i];
}
__global__ void k_gconvT(const float* __restrict__ s, f16* __restrict__ d){
  int id = blockIdx.x;            // k*256+fi : 1280
  int fo = threadIdx.x;           // 256
  d[(size_t)fo*1280 + id] = (f16)s[(size_t)id*256 + fo];
}
__global__ void k_gdecT(const float* __restrict__ s, f16* __restrict__ d){
  int v = blockIdx.x, f = threadIdx.x;    // 2048 x 256
  f16 val = (f16)0.f;
  if (v < 2000) val = (f16)s[(size_t)f*2000 + v];
  d[(size_t)v*256 + f] = val;
}
__global__ void k_epad(const int* __restrict__ xs, const float* __restrict__ gemb, f16* __restrict__ epad){
  int id = blockIdx.x;            // b*516+p
  int f = threadIdx.x;
  int b = id / 516, p = id % 516;
  float v = 0.f;
  if (p >= 2 && p < 514){ int idx = xs[b*512 + p - 2]; v = tanh_c(gemb[(size_t)idx*256 + f]); }
  epad[(size_t)id*256 + f] = (f16)v;
}
__global__ void k_embx(const int* __restrict__ xs, const int* __restrict__ ys,
                       const float* __restrict__ eemb, const float* __restrict__ demb,
                       f16* __restrict__ xo, f16* __restrict__ yo){
  int id = blockIdx.x; int f = threadIdx.x;  // 2*32*512 blocks x 128
  bool dec = id >= 32*512; int id2 = dec ? id - 32*512 : id;
  int idx = dec ? ys[id2] : xs[id2];
  if (idx < 4) idx = 0;
  const float* src = (dec ? demb : eemb) + (size_t)idx*128;
  (dec ? yo : xo)[(size_t)id2*128 + f] = (f16)src[f];
}

// ---------------- LSTM i8 weight prep ----------------
// global absmax of Whh (1024x256 f32) -> ws[0] (u32 bits of positive float)
__global__ void k_wmax(const float* __restrict__ Whh, u32* __restrict__ ws){
  int i = (blockIdx.x*256 + threadIdx.x)*4;
  float m = 0.f;
  #pragma unroll
  for (int j=0;j<4;j++) m = fmaxf(m, fabsf(Whh[i+j]));
  #pragma unroll
  for (int d=1; d<64; d<<=1) m = fmaxf(m, __shfl_xor(m, d, 64));
  if ((threadIdx.x & 63) == 0) atomicMax(ws, __float_as_uint(m));
}
// quantize Whh into i8 MFMA A-fragments.
// frag id = w*64 + tile*4 + kt  (w=row-block 0..3, tile=g*4+uh, kt = K-tile of 64)
// lane l: row = g*256 + w*64 + uh*16 + (l&15); k = kt*64 + (l>>4)*16 + j (j=0..15)
__global__ void k_wq8(const float* __restrict__ Whh, const u32* __restrict__ ws,
                      i32x4* __restrict__ Wq){
  const int bid = blockIdx.x;     // 0..255
  const int l = threadIdx.x;      // 0..63
  const int w = bid >> 6, tile = (bid >> 2) & 15, kt = bid & 3;
  const int g = tile >> 2, uh = tile & 3;
  const int row = g*256 + w*64 + uh*16 + (l & 15);
  const int k0  = kt*64 + (l >> 4)*16;
  const float scale = 127.f / __uint_as_float(ws[0]);
  int dw[4];
  #pragma unroll
  for (int d=0; d<4; d++){
    u32 acc = 0;
    #pragma unroll
    for (int j=0; j<4; j++){
      float q = __builtin_rintf(Whh[(size_t)row*256 + k0 + d*4 + j] * scale);
      int qi = (int)fminf(fmaxf(q, -127.f), 127.f);
      acc |= ((u32)qi & 0xffu) << (8*j);
    }
    dw[d] = (int)acc;
  }
  i32x4 v = { dw[0], dw[1], dw[2], dw[3] };
  Wq[(size_t)bid*64 + l] = v;
}

// ---------------- GEMM kernels ----------------
__global__ __launch_bounds__(256,4) void k_conv(const f16* __restrict__ epad, const f16* __restrict__ gcT, f16* __restrict__ tf){
  __shared__ f16 lA[64*LDT], lB[64*LDT];
  const int m0 = blockIdx.x*64, n0 = blockIdx.y*64;
  const int b = m0 >> 9, n = m0 & 511;
  f32x4 acc[4]; ZERO4(acc);
  gemm64(epad + ((size_t)b*516 + n)*256, 256, gcT + (size_t)n0*1280, 1280, 1280, lA, lB, acc);
  const int lane=threadIdx.x&63, wv=threadIdx.x>>6, l15=lane&15, kq=lane>>4;
  #pragma unroll
  for (int nt=0;nt<4;nt++)
    #pragma unroll
    for (int r=0;r<4;r++)
      tf[(size_t)(m0 + 16*wv + 4*kq + r)*256 + n0 + nt*16 + l15] = (f16)tanh_c(acc[nt][r]);
}

__global__ __launch_bounds__(256,4) void k_u(const f16* __restrict__ X, const f16* __restrict__ Wih,
                                             const float* __restrict__ bias, f16* __restrict__ U){
  __shared__ f16 lA[64*LDT], lB[64*LDT];
  const int m0 = blockIdx.x*64, n0 = blockIdx.y*64;
  f32x4 acc[4]; ZERO4(acc);
  gemm64(X + (size_t)m0*128, 128, Wih + (size_t)n0*128, 128, 128, lA, lB, acc);
  const int lane=threadIdx.x&63, wv=threadIdx.x>>6, l15=lane&15, kq=lane>>4;
  #pragma unroll
  for (int nt=0;nt<4;nt++){
    float bv = bias[n0 + nt*16 + l15];
    #pragma unroll
    for (int r=0;r<4;r++)
      U[(size_t)(m0 + 16*wv + 4*kq + r)*1024 + n0 + nt*16 + l15] = (f16)(acc[nt][r] + bv);
  }
}

__global__ __launch_bounds__(256,4) void k_th(const f16* __restrict__ henh, const f16* __restrict__ Tf, f16* __restrict__ Th){
  __shared__ f16 lA[64*LDT], lB[64*LDT];
  const int m0 = blockIdx.x*64, n0 = blockIdx.y*64;
  f32x4 acc[4]; ZERO4(acc);
  gemm64(henh + (size_t)m0*512, 512, Tf + (size_t)n0*512, 512, 512, lA, lB, acc);
  const int lane=threadIdx.x&63, wv=threadIdx.x>>6, l15=lane&15, kq=lane>>4;
  #pragma unroll
  for (int nt=0;nt<4;nt++)
    #pragma unroll
    for (int r=0;r<4;r++)
      Th[(size_t)(m0 + 16*wv + 4*kq + r)*256 + n0 + nt*16 + l15] = (f16)acc[nt][r];
}

__global__ __launch_bounds__(256,2) void k_pass1(const f16* __restrict__ tf, const f16* __restrict__ gdT,
                                                 float* __restrict__ mxp, float* __restrict__ sep){
  __shared__ f16 lA[64*LDA];
  __shared__ f16 lB[64*LDT];
  __shared__ float mx_s[64], se_s[64];
  const int mt = blockIdx.x, ns = blockIdx.y;
  const int tid = threadIdx.x, lane=tid&63, wv=tid>>6, l15=lane&15, kq=lane>>4;
  {
    const f16* A = tf + (size_t)mt*64*256;
    int row = tid>>2, qq = tid&3;
    #pragma unroll
    for (int c=0;c<8;c++)
      *(f16x8*)(lA + row*LDA + c*32 + qq*8) = *(const f16x8*)(A + (size_t)row*256 + c*32 + qq*8);
  }
  if (tid < 64){ mx_s[tid] = -1e30f; se_s[tid] = 0.f; }
  __syncthreads();
  for (int nc=0; nc<8; nc++){
    const int nbase = ns*512 + nc*64;
    const f16* Bm = gdT + (size_t)nbase*256;
    f32x4 acc[4]; ZERO4(acc);
    for (int k0=0; k0<256; k0+=32){
      __syncthreads();
      stage_tile(Bm + k0, 256, lB);
      __syncthreads();
      f16x8 af = frag_ld(lA + (16*wv + l15)*LDA + k0 + kq*8);
      #pragma unroll
      for (int nt=0; nt<4; nt++){
        f16x8 bf = frag_ld(lB + (16*nt + l15)*LDT + kq*8);
        acc[nt] = __builtin_amdgcn_mfma_f32_16x16x32_f16(af, bf, acc[nt], 0,0,0);
      }
    }
    #pragma unroll
    for (int r=0;r<4;r++){
      float av[4]; float cm = -1e30f;
      #pragma unroll
      for (int nt=0;nt<4;nt++){
        int gcol = nbase + nt*16 + l15;
        float a = (gcol < 2000) ? acc[nt][r] : -1e30f;
        av[nt] = a; cm = fmaxf(cm, a);
      }
      cm = wmax16(cm);
      int rr = 16*wv + 4*kq + r;
      float old = mx_s[rr];
      float nm = fmaxf(old, cm);
      float ss = 0.f;
      #pragma unroll
      for (int nt=0;nt<4;nt++) ss += __expf(av[nt] - nm);
      ss = wsum16(ss);
      if (l15 == 0){
        se_s[rr] = se_s[rr]*__expf(old - nm) + ss;
        mx_s[rr] = nm;
      }
    }
  }
  __syncthreads();
  if (tid < 64){
    mxp[(size_t)ns*16384 + mt*64 + tid] = mx_s[tid];
    sep[(size_t)ns*16384 + mt*64 + tid] = se_s[tid];
  }
}

__global__ void k_comb1(const float* __restrict__ mxp, const float* __restrict__ sep,
                        float* __restrict__ mx, float* __restrict__ se){
  int m = blockIdx.x*256 + threadIdx.x;
  float best = -1e30f;
  #pragma unroll
  for (int k=0;k<4;k++) best = fmaxf(best, mxp[(size_t)k*16384 + m]);
  float s = 0.f;
  #pragma unroll
  for (int k=0;k<4;k++) s += sep[(size_t)k*16384 + m] * __expf(mxp[(size_t)k*16384 + m] - best);
  mx[m] = best; se[m] = s;
}

__global__ __launch_bounds__(256,4) void k_pass2(const f16* __restrict__ tf, const f16* __restrict__ gdT,
                                                 const int* __restrict__ ys, const float* __restrict__ mx,
                                                 const float* __restrict__ se, f16* __restrict__ scT){
  __shared__ f16 lA[64*LDT], lB[64*LDT];
  __shared__ int jv[64];
  const int it = blockIdx.x, jt = blockIdx.y, b = blockIdx.z;
  const int tid = threadIdx.x, lane=tid&63, wv=tid>>6, l15=lane&15, kq=lane>>4;
  if (tid<64) jv[tid] = ys[b*512 + jt*64 + tid];
  const f16* A = tf + ((size_t)b*512 + it*64)*256;
  f32x4 acc[4]; ZERO4(acc);
  for (int k0=0;k0<256;k0+=32){
    __syncthreads();
    stage_tile(A + k0, 256, lA);
    { int row=tid>>2, qq=tid&3;
      *(f16x8*)(lB + row*LDT + qq*8) = *(const f16x8*)(gdT + (size_t)jv[row]*256 + k0 + qq*8); }
    __syncthreads();
    f16x8 af = frag_ld(lA + (16*wv+l15)*LDT + kq*8);
    #pragma unroll
    for (int nt=0;nt<4;nt++){
      f16x8 bf = frag_ld(lB + (16*nt+l15)*LDT + kq*8);
      acc[nt] = __builtin_amdgcn_mfma_f32_16x16x32_f16(af, bf, acc[nt], 0,0,0);
    }
  }
  float mxv[4], rsev[4];
  #pragma unroll
  for (int r=0;r<4;r++){
    int i_ = it*64 + 16*wv + 4*kq + r;
    mxv[r] = mx[b*512 + i_];
    rsev[r] = 1.f / se[b*512 + i_];
  }
  #pragma unroll
  for (int nt=0;nt<4;nt++){
    int j_ = jt*64 + nt*16 + l15;
    #pragma unroll
    for (int r=0;r<4;r++){
      int i_ = it*64 + 16*wv + 4*kq + r;
      scT[((size_t)b*512 + j_)*512 + i_] = (f16)(__expf(acc[nt][r] - mxv[r]) * rsev[r]);
    }
  }
}

__global__ __launch_bounds__(256,2) void k_final(const f16* __restrict__ hdec, const f16* __restrict__ Th,
                                                 const f16* __restrict__ scT,
                                                 float* __restrict__ pmx, float* __restrict__ pden, float* __restrict__ pnum){
  __shared__ f16 lA[64*LDA];
  __shared__ f16 lB[64*LDT];
  __shared__ float mx_s[64], den_s[64], num_s[64];
  const int is = blockIdx.x, jt = blockIdx.y, b = blockIdx.z;
  const int tid = threadIdx.x, lane=tid&63, wv=tid>>6, l15=lane&15, kq=lane>>4;
  {
    const f16* A = hdec + ((size_t)b*512 + jt*64)*256;
    int row = tid>>2, qq = tid&3;
    #pragma unroll
    for (int c=0;c<8;c++)
      *(f16x8*)(lA + row*LDA + c*32 + qq*8) = *(const f16x8*)(A + (size_t)row*256 + c*32 + qq*8);
  }
  if (tid<64){ mx_s[tid]=-1e30f; den_s[tid]=0.f; num_s[tid]=0.f; }
  __syncthreads();
  for (int ic=0; ic<4; ic++){
    const int i0 = is*256 + ic*64;
    const f16* Bm = Th + ((size_t)b*512 + i0)*256;
    f32x4 acc[4]; ZERO4(acc);
    for (int k0=0;k0<256;k0+=32){
      __syncthreads();
      stage_tile(Bm + k0, 256, lB);
      __syncthreads();
      f16x8 af = frag_ld(lA + (16*wv+l15)*LDA + k0 + kq*8);
      #pragma unroll
      for (int nt=0;nt<4;nt++){
        f16x8 bf = frag_ld(lB + (16*nt+l15)*LDT + kq*8);
        acc[nt] = __builtin_amdgcn_mfma_f32_16x16x32_f16(af, bf, acc[nt], 0,0,0);
      }
    }
    #pragma unroll
    for (int r=0;r<4;r++){
      int jl = 16*wv + 4*kq + r;
      float av[4]; float cm=-1e30f;
      #pragma unroll
      for (int nt=0;nt<4;nt++){ av[nt]=acc[nt][r]; cm=fmaxf(cm,av[nt]); }
      cm = wmax16(cm);
      float old = mx_s[jl], nm = fmaxf(old, cm);
      float ds=0.f, nsum=0.f;
      const size_t srow = ((size_t)b*512 + jt*64 + jl)*512;
      #pragma unroll
      for (int nt=0;nt<4;nt++){
        float e = __expf(av[nt]-nm);
        float sc = (float)scT[srow + i0 + nt*16 + l15];
        ds += e; nsum += sc*e;
      }
      ds = wsum16(ds); nsum = wsum16(nsum);
      if (l15==0){
        float fac = __expf(old-nm);
        den_s[jl] = den_s[jl]*fac + ds;
        num_s[jl] = num_s[jl]*fac + nsum;
        mx_s[jl] = nm;
      }
    }
  }
  __syncthreads();
  if (tid<64){
    size_t idx = (((size_t)b*512) + jt*64 + tid)*2 + is;
    pmx[idx]=mx_s[tid]; pden[idx]=den_s[tid]; pnum[idx]=num_s[tid];
  }
}

__global__ void k_comb2(const float* __restrict__ pmx, const float* __restrict__ pden,
                        const float* __restrict__ pnum, float* __restrict__ out){
  const int b = blockIdx.x, j = threadIdx.x;    // 32 x 512
  size_t base = ((size_t)b*512 + j)*2;
  float m0=pmx[base], m1=pmx[base+1];
  float m = fmaxf(m0,m1);
  float e0=__expf(m0-m), e1=__expf(m1-m);
  float den = pden[base]*e0 + pden[base+1]*e1;
  float num = pnum[base]*e0 + pnum[base+1]*e1;
  float lp = __logf(num) - __logf(den);
  __shared__ float red[512];
  red[j] = lp;
  __syncthreads();
  for (int st=256; st>0; st>>=1){ if (j<st) red[j]+=red[j+st]; __syncthreads(); }
  if (j==0) atomicAdd(out, -red[0]);
}

// ---------------- LSTM v6: 8 waves (2/SIMD), i8 MFMA, half weight block per wave ----------------
// 512 thr. Wave wv: row-block w2=wv>>1, uh-pair pw=wv&1 -> tiles (g, pw*2+j), j=0,1 -> 32 frags
// (128 AGPR). B cols replicated: col n = seq n&3. Thread: s=l15&3, p=l15>>2; jt=p&1 picks the
// uh within the pair, rep=p>>1 is a 2-way redundant replica (writes gated on rep==0).
// Units: ub = w2*64 + (pw*2+jt)*16 + kq*4 (+0..3). One __syncthreads per step.
__global__ __launch_bounds__(512,2) void k_lstm6(
    const f16* __restrict__ U, const i32x4* __restrict__ Wq, const u32* __restrict__ ws,
    u16* __restrict__ hout, float* __restrict__ hTcT,
    u16* __restrict__ hdec0, int nsteps, int mode)
{
  __shared__ __align__(16) f16 Ub[2][4*1032];     // staged U, stride 1032 (bank spread)
  __shared__ __align__(16) char h8[2][4*272];     // quantized h, stride 272

  const int tid = threadIdx.x;
  const int lane = tid & 63, wv = tid >> 6;
  const int w2 = wv >> 1, pw = wv & 1;
  const int l15 = lane & 15, kq = lane >> 4;
  const int s = l15 & 3, p = l15 >> 2;
  const int jt = p & 1, rep = p >> 1;
  const int ub = w2*64 + (pw*2 + jt)*16 + kq*4;

  int dir = 0, b0;
  if (mode == 0){ dir = blockIdx.x >> 3; b0 = (blockIdx.x & 7)*4; }
  else b0 = blockIdx.x*4;

  const float zscale = __uint_as_float(ws[0]) * (1.f/(127.f*127.f));

  // A-fragments: 8 tiles (g,j) x 4 kt = 32 frags (MFMA-only use -> AGPR)
  i32x4 aw[32];
  #pragma unroll
  for (int g=0; g<4; g++)
    #pragma unroll
    for (int j=0; j<2; j++)
      #pragma unroll
      for (int kt=0; kt<4; kt++)
        aw[(g*2+j)*4 + kt] = Wq[(size_t)(w2*64 + (g*4 + pw*2 + j)*4 + kt)*64 + lane];

  // init h / c
  float cst[4];
  if (mode == 0){
    #pragma unroll
    for (int r=0;r<4;r++) cst[r] = 0.f;
    for (int i = tid; i < 544; i += 512) ((u32*)h8)[i] = 0u;
  } else {
    const float* hp = hTcT + (size_t)(b0+s)*512;
    float4 hv = *(const float4*)(hp + ub);
    float4 cv = *(const float4*)(hp + 256 + ub);
    cst[0]=cv.x; cst[1]=cv.y; cst[2]=cv.z; cst[3]=cv.w;
    float hvv[4] = {hv.x, hv.y, hv.z, hv.w};
    u32 pk = 0;
    #pragma unroll
    for (int r=0;r<4;r++){
      int q = (int)__builtin_rintf(hvv[r]*127.f);
      pk |= ((u32)q & 0xffu) << (8*r);
    }
    if (rep == 0) *(u32*)&h8[0][s*272 + ub] = pk;
  }

  // stage U for step 0: 512 threads x 16B = 8KB = full buffer
  const int s_st = tid >> 7, col = (tid & 127)*8;
  {
    int tp0 = dir ? (nsteps-1) : 0;
    *(int4*)&Ub[0][s_st*1032 + col] =
      *(const int4*)(U + ((size_t)(b0+s_st)*512 + tp0)*1024 + col);
  }
  __syncthreads();

  int cur = 0;
  #pragma unroll 1
  for (int t=0; t<nsteps; ++t){
    const int tpos = dir ? (nsteps-1-t) : t;

    // prefetch next-step U (global, consumed at loop bottom)
    int tn = dir ? max(nsteps-2-t, 0) : min(t+1, nsteps-1);
    int4 pu = *(const int4*)(U + ((size_t)(b0+s_st)*512 + tn)*1024 + col);

    // B-fragments (replicated cols -> LDS broadcast reads)
    i32x4 bf[4];
    #pragma unroll
    for (int kt=0; kt<4; kt++)
      bf[kt] = *(const i32x4*)&h8[cur][s*272 + kt*64 + kq*16];

    // MFMA: 8 tiles x 4 K-chunks
    i32x4 acc[8];
    #pragma unroll
    for (int tile=0; tile<8; tile++){
      i32x4 d = {0,0,0,0};
      #pragma unroll
      for (int kt=0; kt<4; kt++)
        d = __builtin_amdgcn_mfma_i32_16x16x64_i8(aw[tile*4+kt], bf[kt], d, 0,0,0);
      acc[tile] = d;
    }

    // own U pre-activations (4 gates x 4 units)
    int2 uvg[4];
    #pragma unroll
    for (int g=0; g<4; g++)
      uvg[g] = *(const int2*)&Ub[cur][s*1032 + g*256 + ub];

    // epilogue: units ub+r, seq s (2-way replica-redundant)
    float hv[4];
    #pragma unroll
    for (int r=0; r<4; r++){
      float z[4];
      #pragma unroll
      for (int g=0; g<4; g++){
        int av = jt ? acc[g*2+1][r] : acc[g*2+0][r];
        const f16* uptr = (const f16*)&uvg[g];
        z[g] = fmaf((float)av, zscale, (float)uptr[r]);
      }
      float ig = sig_f(z[0]);
      float fg = sig_f(z[1]);
      float gg = tanh_f(z[2]);
      float og = sig_f(z[3]);
      cst[r] = fg*cst[r] + ig*gg;
      hv[r] = og*tanh_f(cst[r]);
    }

    // pack h -> i8 (LDS, next buffer) and f16 (global)
    u32 pk = 0; u32 hf01, hf23;
    {
      u16 hb[4];
      #pragma unroll
      for (int r=0;r<4;r++){
        int q = (int)__builtin_rintf(hv[r]*127.f);
        pk |= ((u32)q & 0xffu) << (8*r);
        f16 hf = (f16)hv[r];
        hb[r] = __builtin_bit_cast(u16, hf);
      }
      hf01 = (u32)hb[0] | ((u32)hb[1] << 16);
      hf23 = (u32)hb[2] | ((u32)hb[3] << 16);
    }
    const int nxt = cur ^ 1;
    if (rep == 0) *(u32*)&h8[nxt][s*272 + ub] = pk;
    // stage prefetched U into next buffer
    *(int4*)&Ub[nxt][s_st*1032 + col] = pu;

    if (rep == 0){
      int2 hh = { (int)hf01, (int)hf23 };
      if (mode == 0){
        *(int2*)(hout + ((size_t)(b0+s)*512 + tpos)*512 + dir*256 + ub) = hh;
        if (!dir && t == nsteps-1){
          *(int2*)(hdec0 + (size_t)(b0+s)*512*256 + ub) = hh;
          float* hp = hTcT + (size_t)(b0+s)*512;
          *(float4*)(hp + ub) = make_float4(hv[0], hv[1], hv[2], hv[3]);
          *(float4*)(hp + 256 + ub) = make_float4(cst[0], cst[1], cst[2], cst[3]);
        }
      } else {
        *(int2*)(hout + ((size_t)(b0+s)*512 + (t+1))*256 + ub) = hh;
      }
    }
    __syncthreads();
    cur = nxt;
  }
}

// ---------------- host ----------------
extern "C" void kernel_launch(void* const* d_in, const int* in_sizes, int n_in,
                              void* d_out, int out_size, void* d_ws, size_t ws_size,
                              hipStream_t stream)
{
  (void)in_sizes; (void)n_in; (void)out_size;
  const int*   xs    = (const int*)d_in[0];
  const int*   ys    = (const int*)d_in[1];
  const float* gemb  = (const float*)d_in[2];
  const float* gconv = (const float*)d_in[3];
  const float* gdec  = (const float*)d_in[4];
  const float* eemb  = (const float*)d_in[5];
  const float* demb  = (const float*)d_in[6];
  const float* eWih  = (const float*)d_in[7];
  const float* eWhh  = (const float*)d_in[8];
  const float* eb    = (const float*)d_in[9];
  const float* dWih  = (const float*)d_in[10];
  const float* dWhh  = (const float*)d_in[11];
  const float* db    = (const float*)d_in[12];
  const float* Tm    = (const float*)d_in[13];

  char* wsb = (char*)d_ws;
  size_t off = 0;
  auto take = [&](size_t bytes)->char*{ char* p = wsb + off; off += (bytes + 255) & ~(size_t)255; return p; };
  f16* epad  = (f16*)take((size_t)32*516*256*2);
  f16* tf    = (f16*)take((size_t)32*512*256*2);
  f16* xemb  = (f16*)take((size_t)32*512*128*2);
  f16* yemb  = (f16*)take((size_t)32*512*128*2);
  f16* Uenc  = (f16*)take((size_t)32*512*1024*2);
  f16* Udec  = (f16*)take((size_t)32*512*1024*2);
  f16* henh  = (f16*)take((size_t)32*512*512*2);
  f16* hdec  = (f16*)take((size_t)32*512*256*2);
  f16* Th    = (f16*)take((size_t)32*512*256*2);
  f16* scT   = (f16*)take((size_t)32*512*512*2);
  float* mx  = (float*)take((size_t)16384*4);
  float* se  = (float*)take((size_t)16384*4);
  float* mxp = (float*)take((size_t)4*16384*4);
  float* sep = (float*)take((size_t)4*16384*4);
  float* pmx = (float*)take((size_t)32*512*2*4);
  float* pden= (float*)take((size_t)32*512*2*4);
  float* pnum= (float*)take((size_t)32*512*2*4);
  float* hTcT= (float*)take((size_t)32*512*4);
  f16* Wihe  = (f16*)take((size_t)1024*128*2);
  f16* Wihd  = (f16*)take((size_t)1024*128*2);
  f16* Tf    = (f16*)take((size_t)256*512*2);
  f16* gcT   = (f16*)take((size_t)256*1280*2);
  f16* gdT   = (f16*)take((size_t)2048*256*2);
  i32x4* Wq8e = (i32x4*)take((size_t)256*64*16);
  i32x4* Wq8d = (i32x4*)take((size_t)256*64*16);
  u32* wsc   = (u32*)take(8);
  if (off > ws_size) return;  // insufficient scratch -> visible as wrong answer

  hipMemsetAsync(d_out, 0, sizeof(float), stream);
  hipMemsetAsync(wsc, 0, 8, stream);

  // weight conversions / quantization
  k_cvt<<<dim3(512),  256, 0, stream>>>(eWih, Wihe, 1024*128);
  k_cvt<<<dim3(512),  256, 0, stream>>>(dWih, Wihd, 1024*128);
  k_cvt<<<dim3(512),  256, 0, stream>>>(Tm,   Tf,   256*512);
  k_gconvT<<<dim3(1280), 256, 0, stream>>>(gconv, gcT);
  k_gdecT <<<dim3(2048), 256, 0, stream>>>(gdec, gdT);
  k_wmax<<<dim3(256), 256, 0, stream>>>(eWhh, wsc + 0);
  k_wmax<<<dim3(256), 256, 0, stream>>>(dWhh, wsc + 1);
  k_wq8<<<dim3(256), 64, 0, stream>>>(eWhh, wsc + 0, Wq8e);
  k_wq8<<<dim3(256), 64, 0, stream>>>(dWhh, wsc + 1, Wq8d);

  // embeddings
  k_epad<<<dim3(32*516), 256, 0, stream>>>(xs, gemb, epad);
  k_embx<<<dim3(2*32*512), 128, 0, stream>>>(xs, ys, eemb, demb, xemb, yemb);

  // G-stack
  k_conv<<<dim3(256,4), 256, 0, stream>>>(epad, gcT, tf);
  k_pass1<<<dim3(256,4), 256, 0, stream>>>(tf, gdT, mxp, sep);
  k_comb1<<<dim3(64), 256, 0, stream>>>(mxp, sep, mx, se);
  k_pass2<<<dim3(8,8,32), 256, 0, stream>>>(tf, gdT, ys, mx, se, scT);

  // LSTM input-gate precompute
  k_u<<<dim3(256,16), 256, 0, stream>>>(xemb, Wihe, eb, Uenc);
  k_u<<<dim3(256,16), 256, 0, stream>>>(yemb, Wihd, db, Udec);

  // recurrences: 16 WGs enc (8 fwd + 8 bwd quads), 8 WGs dec; 512 thr, 2 waves/SIMD
  k_lstm6<<<dim3(16), 512, 0, stream>>>(Uenc, Wq8e, wsc + 0, (u16*)henh, hTcT, (u16*)hdec, 512, 0);
  k_lstm6<<<dim3(8),  512, 0, stream>>>(Udec, Wq8d, wsc + 1, (u16*)hdec, hTcT, (u16*)hdec, 511, 1);

  // alignment
  k_th<<<dim3(256,4), 256, 0, stream>>>(henh, Tf, Th);
  k_final<<<dim3(2,8,32), 256, 0, stream>>>(hdec, Th, scT, pmx, pden, pnum);
  k_comb2<<<dim3(32), 512, 0, stream>>>(pmx, pden, pnum, (float*)d_out);
}

// Round 8
// 1181.637 us; speedup vs baseline: 3.3937x; 1.4094x over previous
//
#include <hip/hip_runtime.h>

typedef _Float16 f16;
typedef _Float16 f16x2 __attribute__((ext_vector_type(2)));
typedef _Float16 f16x8 __attribute__((ext_vector_type(8)));
typedef float    f32x4 __attribute__((ext_vector_type(4)));
typedef int      i32x4 __attribute__((ext_vector_type(4)));
typedef unsigned int u32;
typedef unsigned short u16;

#define DEVI static __device__ __forceinline__

static constexpr int LDT = 40;    // lds row stride (halves) for 64x32 tiles (+8 pad)
static constexpr int LDA = 264;   // lds row stride for 64x256 resident A tiles

DEVI float sigf(float x){ return 1.f/(1.f + __expf(-x)); }
DEVI float tanh_c(float x){
  x = fminf(fmaxf(x, -15.f), 15.f);
  float e = __expf(2.f*x);
  return (e - 1.f)/(e + 1.f);
}
DEVI float sig_f(float x){ return __builtin_amdgcn_rcpf(1.f + __expf(-x)); }
DEVI float tanh_f(float x){ return 1.f - 2.f*__builtin_amdgcn_rcpf(1.f + __expf(2.f*x)); }
DEVI float wmax16(float v){
  #pragma unroll
  for (int m=1;m<16;m<<=1) v = fmaxf(v, __shfl_xor(v, m, 64));
  return v;
}
DEVI float wsum16(float v){
  #pragma unroll
  for (int m=1;m<16;m<<=1) v += __shfl_xor(v, m, 64);
  return v;
}
DEVI f16x8 frag_ld(const f16* p){ return *(const f16x8*)p; }
DEVI void stage_tileh(int t256, const f16* src, int ld, f16* dst){
  int row = t256>>2, qq = t256&3;
  *(f16x8*)(dst + row*LDT + qq*8) = *(const f16x8*)(src + (size_t)row*ld + qq*8);
}
#define ZERO4(acc) { f32x4 _z = {0.f,0.f,0.f,0.f}; acc[0]=_z; acc[1]=_z; acc[2]=_z; acc[3]=_z; }

// 64x64 NT MFMA tile (t256 = thread id within the 256-thread tile team)
DEVI void gemm64h(int t256, const f16* A, int lda, const f16* Bm, int ldb, int K,
                  f16* lA, f16* lB, f32x4 acc[4]){
  const int lane = t256 & 63, wv = t256 >> 6;
  const int l15 = lane & 15, kq = lane >> 4;
  for (int k0=0; k0<K; k0+=32){
    __syncthreads();
    stage_tileh(t256, A + k0, lda, lA);
    stage_tileh(t256, Bm + k0, ldb, lB);
    __syncthreads();
    f16x8 af = frag_ld(lA + (16*wv + l15)*LDT + kq*8);
    #pragma unroll
    for (int nt=0; nt<4; nt++){
      f16x8 bf = frag_ld(lB + (16*nt + l15)*LDT + kq*8);
      acc[nt] = __builtin_amdgcn_mfma_f32_16x16x32_f16(af, bf, acc[nt], 0,0,0);
    }
  }
}

// ---------------- small prep kernels ----------------
__global__ void k_cvt(const float* __restrict__ s, f16* __restrict__ d, int n){
  int i = blockIdx.x*256 + threadIdx.x;
  if (i < n) d[i] = (f16)s[i];
}
__global__ void k_gconvT(const float* __restrict__ s, f16* __restrict__ d){
  int id = blockIdx.x;            // k*256+fi : 1280
  int fo = threadIdx.x;           // 256
  d[(size_t)fo*1280 + id] = (f16)s[(size_t)id*256 + fo];
}
__global__ void k_gdecT(const float* __restrict__ s, f16* __restrict__ d){
  int v = blockIdx.x, f = threadIdx.x;    // 2048 x 256
  f16 val = (f16)0.f;
  if (v < 2000) val = (f16)s[(size_t)f*2000 + v];
  d[(size_t)v*256 + f] = val;
}
__global__ void k_epad(const int* __restrict__ xs, const float* __restrict__ gemb, f16* __restrict__ epad){
  int id = blockIdx.x;            // b*516+p
  int f = threadIdx.x;
  int b = id / 516, p = id % 516;
  float v = 0.f;
  if (p >= 2 && p < 514){ int idx = xs[b*512 + p - 2]; v = tanh_c(gemb[(size_t)idx*256 + f]); }
  epad[(size_t)id*256 + f] = (f16)v;
}
__global__ void k_embx(const int* __restrict__ xs, const int* __restrict__ ys,
                       const float* __restrict__ eemb, const float* __restrict__ demb,
                       f16* __restrict__ xo, f16* __restrict__ yo){
  int id = blockIdx.x; int f = threadIdx.x;  // 2*32*512 blocks x 128
  bool dec = id >= 32*512; int id2 = dec ? id - 32*512 : id;
  int idx = dec ? ys[id2] : xs[id2];
  if (idx < 4) idx = 0;
  const float* src = (dec ? demb : eemb) + (size_t)idx*128;
  (dec ? yo : xo)[(size_t)id2*128 + f] = (f16)src[f];
}

// ---------------- LSTM i8 weight prep ----------------
__global__ void k_wmax(const float* __restrict__ Whh, u32* __restrict__ ws){
  int i = (blockIdx.x*256 + threadIdx.x)*4;
  float m = 0.f;
  #pragma unroll
  for (int j=0;j<4;j++) m = fmaxf(m, fabsf(Whh[i+j]));
  #pragma unroll
  for (int d=1; d<64; d<<=1) m = fmaxf(m, __shfl_xor(m, d, 64));
  if ((threadIdx.x & 63) == 0) atomicMax(ws, __float_as_uint(m));
}
// quantize Whh into gate-packed i8 MFMA A-fragments.
// bid = (w*8 + t8)*4 + kt; lane l: r15=l&15 -> u4=r15>>2, g=r15&3;
// unit = w*32 + t8*4 + u4; source row = g*256 + unit; k = kt*64 + (l>>4)*16 + (0..15)
__global__ void k_wq8(const float* __restrict__ Whh, const u32* __restrict__ ws,
                      i32x4* __restrict__ Wq){
  const int bid = blockIdx.x;     // 0..255
  const int l = threadIdx.x;      // 0..63
  const int kt = bid & 3, t8 = (bid >> 2) & 7, w = bid >> 5;
  const int r15 = l & 15;
  const int u4 = r15 >> 2, g = r15 & 3;
  const int unit = w*32 + t8*4 + u4;
  const int row = g*256 + unit;
  const int k0  = kt*64 + (l >> 4)*16;
  const float scale = 127.f / __uint_as_float(ws[0]);
  int dw[4];
  #pragma unroll
  for (int d=0; d<4; d++){
    u32 acc = 0;
    #pragma unroll
    for (int j=0; j<4; j++){
      float q = __builtin_rintf(Whh[(size_t)row*256 + k0 + d*4 + j] * scale);
      int qi = (int)fminf(fmaxf(q, -127.f), 127.f);
      acc |= ((u32)qi & 0xffu) << (8*j);
    }
    dw[d] = (int)acc;
  }
  i32x4 v = { dw[0], dw[1], dw[2], dw[3] };
  Wq[(size_t)bid*64 + l] = v;
}

// ---------------- GEMM bodies ----------------
__global__ __launch_bounds__(256,4) void k_conv(const f16* __restrict__ epad, const f16* __restrict__ gcT, f16* __restrict__ tf){
  __shared__ f16 lA[64*LDT], lB[64*LDT];
  const int m0 = blockIdx.x*64, n0 = blockIdx.y*64;
  const int b = m0 >> 9, n = m0 & 511;
  f32x4 acc[4]; ZERO4(acc);
  gemm64h(threadIdx.x, epad + ((size_t)b*516 + n)*256, 256, gcT + (size_t)n0*1280, 1280, 1280, lA, lB, acc);
  const int lane=threadIdx.x&63, wv=threadIdx.x>>6, l15=lane&15, kq=lane>>4;
  #pragma unroll
  for (int nt=0;nt<4;nt++)
    #pragma unroll
    for (int r=0;r<4;r++)
      tf[(size_t)(m0 + 16*wv + 4*kq + r)*256 + n0 + nt*16 + l15] = (f16)tanh_c(acc[nt][r]);
}

// U output permuted to unit-major: col' = unit*4 + gate
DEVI void ku_body(int t256, int m0, int n0, const f16* X, const f16* Wih,
                  const float* bias, f16* U, f16* lA, f16* lB){
  f32x4 acc[4]; ZERO4(acc);
  gemm64h(t256, X + (size_t)m0*128, 128, Wih + (size_t)n0*128, 128, 128, lA, lB, acc);
  const int lane=t256&63, wv=t256>>6, l15=lane&15, kq=lane>>4;
  #pragma unroll
  for (int nt=0;nt<4;nt++){
    int n = n0 + nt*16 + l15;
    float bv = bias[n];
    int cnew = (n & 255)*4 + (n >> 8);
    #pragma unroll
    for (int r=0;r<4;r++)
      U[(size_t)(m0 + 16*wv + 4*kq + r)*1024 + cnew] = (f16)(acc[nt][r] + bv);
  }
}

__global__ __launch_bounds__(256,4) void k_u(const f16* __restrict__ X, const f16* __restrict__ Wih,
                                             const float* __restrict__ bias, f16* __restrict__ U){
  __shared__ f16 lA[64*LDT], lB[64*LDT];
  ku_body(threadIdx.x, blockIdx.x*64, blockIdx.y*64, X, Wih, bias, U, lA, lB);
}

DEVI void th_body(int t256, int m0, int n0, const f16* henh, const f16* Tf, f16* Th,
                  f16* lA, f16* lB){
  f32x4 acc[4]; ZERO4(acc);
  gemm64h(t256, henh + (size_t)m0*512, 512, Tf + (size_t)n0*512, 512, 512, lA, lB, acc);
  const int lane=t256&63, wv=t256>>6, l15=lane&15, kq=lane>>4;
  #pragma unroll
  for (int nt=0;nt<4;nt++)
    #pragma unroll
    for (int r=0;r<4;r++)
      Th[(size_t)(m0 + 16*wv + 4*kq + r)*256 + n0 + nt*16 + l15] = (f16)acc[nt][r];
}

// pass1 (512-thr): halves split the 8 n-chunks; shared lA; per-half lB/mx/se; merged at end
DEVI void pass1_body(int tid, int mt, int ns, const f16* tf, const f16* gdT,
                     float* mxp, float* sep, f16* lA, f16* lB2, float* mxs2, float* ses2){
  const int half = tid >> 8, t256 = tid & 255;
  const int lane = tid & 63, wv = t256 >> 6, l15 = lane & 15, kq = lane >> 4;
  f16* lB = lB2 + half*(64*LDT);
  {
    const f16* A = tf + (size_t)mt*64*256;
    int row = tid >> 3, c8 = tid & 7;
    #pragma unroll
    for (int q=0;q<4;q++)
      *(f16x8*)(lA + row*LDA + c8*32 + q*8) = *(const f16x8*)(A + (size_t)row*256 + c8*32 + q*8);
  }
  if (t256 < 64){ mxs2[half*64 + t256] = -1e30f; ses2[half*64 + t256] = 0.f; }
  __syncthreads();
  for (int nci=0; nci<4; nci++){
    const int nc = half*4 + nci;
    const int nbase = ns*512 + nc*64;
    const f16* Bm = gdT + (size_t)nbase*256;
    f32x4 acc[4]; ZERO4(acc);
    for (int k0=0; k0<256; k0+=32){
      __syncthreads();
      stage_tileh(t256, Bm + k0, 256, lB);
      __syncthreads();
      f16x8 af = frag_ld(lA + (16*wv + l15)*LDA + k0 + kq*8);
      #pragma unroll
      for (int nt=0; nt<4; nt++){
        f16x8 bf = frag_ld(lB + (16*nt + l15)*LDT + kq*8);
        acc[nt] = __builtin_amdgcn_mfma_f32_16x16x32_f16(af, bf, acc[nt], 0,0,0);
      }
    }
    #pragma unroll
    for (int r=0;r<4;r++){
      float av[4]; float cm = -1e30f;
      #pragma unroll
      for (int nt=0;nt<4;nt++){
        int gcol = nbase + nt*16 + l15;
        float a = (gcol < 2000) ? acc[nt][r] : -1e30f;
        av[nt] = a; cm = fmaxf(cm, a);
      }
      cm = wmax16(cm);
      int rr = half*64 + 16*wv + 4*kq + r;
      float old = mxs2[rr];
      float nm = fmaxf(old, cm);
      float ss = 0.f;
      #pragma unroll
      for (int nt=0;nt<4;nt++) ss += __expf(av[nt] - nm);
      ss = wsum16(ss);
      if (l15 == 0){
        ses2[rr] = ses2[rr]*__expf(old - nm) + ss;
        mxs2[rr] = nm;
      }
    }
  }
  __syncthreads();
  if (tid < 64){
    float m0 = mxs2[tid], m1 = mxs2[64+tid];
    float nm = fmaxf(m0, m1);
    float se = ses2[tid]*__expf(m0-nm) + ses2[64+tid]*__expf(m1-nm);
    mxp[(size_t)ns*16384 + mt*64 + tid] = nm;
    sep[(size_t)ns*16384 + mt*64 + tid] = se;
  }
}

__global__ void k_comb1(const float* __restrict__ mxp, const float* __restrict__ sep,
                        float* __restrict__ mx, float* __restrict__ se){
  int m = blockIdx.x*256 + threadIdx.x;
  float best = -1e30f;
  #pragma unroll
  for (int k=0;k<4;k++) best = fmaxf(best, mxp[(size_t)k*16384 + m]);
  float s = 0.f;
  #pragma unroll
  for (int k=0;k<4;k++) s += sep[(size_t)k*16384 + m] * __expf(mxp[(size_t)k*16384 + m] - best);
  mx[m] = best; se[m] = s;
}

DEVI void pass2_body(int t256, int it, int jt, int b, const f16* tf, const f16* gdT,
                     const int* ys, const float* mx, const float* se, f16* scT,
                     f16* lA, f16* lB, int* jv){
  const int lane=t256&63, wv=t256>>6, l15=lane&15, kq=lane>>4;
  if (t256<64) jv[t256] = ys[b*512 + jt*64 + t256];
  const f16* A = tf + ((size_t)b*512 + it*64)*256;
  f32x4 acc[4]; ZERO4(acc);
  for (int k0=0;k0<256;k0+=32){
    __syncthreads();
    stage_tileh(t256, A + k0, 256, lA);
    { int row=t256>>2, qq=t256&3;
      *(f16x8*)(lB + row*LDT + qq*8) = *(const f16x8*)(gdT + (size_t)jv[row]*256 + k0 + qq*8); }
    __syncthreads();
    f16x8 af = frag_ld(lA + (16*wv+l15)*LDT + kq*8);
    #pragma unroll
    for (int nt=0;nt<4;nt++){
      f16x8 bf = frag_ld(lB + (16*nt+l15)*LDT + kq*8);
      acc[nt] = __builtin_amdgcn_mfma_f32_16x16x32_f16(af, bf, acc[nt], 0,0,0);
    }
  }
  float mxv[4], rsev[4];
  #pragma unroll
  for (int r=0;r<4;r++){
    int i_ = it*64 + 16*wv + 4*kq + r;
    mxv[r] = mx[b*512 + i_];
    rsev[r] = 1.f / se[b*512 + i_];
  }
  #pragma unroll
  for (int nt=0;nt<4;nt++){
    int j_ = jt*64 + nt*16 + l15;
    #pragma unroll
    for (int r=0;r<4;r++){
      int i_ = it*64 + 16*wv + 4*kq + r;
      scT[((size_t)b*512 + j_)*512 + i_] = (f16)(__expf(acc[nt][r] - mxv[r]) * rsev[r]);
    }
  }
}

__global__ __launch_bounds__(256,2) void k_final(const f16* __restrict__ hdec, const f16* __restrict__ Th,
                                                 const f16* __restrict__ scT,
                                                 float* __restrict__ pmx, float* __restrict__ pden, float* __restrict__ pnum){
  __shared__ f16 lA[64*LDA];
  __shared__ f16 lB[64*LDT];
  __shared__ float mx_s[64], den_s[64], num_s[64];
  const int is = blockIdx.x, jt = blockIdx.y, b = blockIdx.z;
  const int tid = threadIdx.x, lane=tid&63, wv=tid>>6, l15=lane&15, kq=lane>>4;
  {
    const f16* A = hdec + ((size_t)b*512 + jt*64)*256;
    int row = tid>>2, qq = tid&3;
    #pragma unroll
    for (int c=0;c<8;c++)
      *(f16x8*)(lA + row*LDA + c*32 + qq*8) = *(const f16x8*)(A + (size_t)row*256 + c*32 + qq*8);
  }
  if (tid<64){ mx_s[tid]=-1e30f; den_s[tid]=0.f; num_s[tid]=0.f; }
  __syncthreads();
  for (int ic=0; ic<4; ic++){
    const int i0 = is*256 + ic*64;
    const f16* Bm = Th + ((size_t)b*512 + i0)*256;
    f32x4 acc[4]; ZERO4(acc);
    for (int k0=0;k0<256;k0+=32){
      __syncthreads();
      stage_tileh(tid, Bm + k0, 256, lB);
      __syncthreads();
      f16x8 af = frag_ld(lA + (16*wv+l15)*LDA + k0 + kq*8);
      #pragma unroll
      for (int nt=0;nt<4;nt++){
        f16x8 bf = frag_ld(lB + (16*nt+l15)*LDT + kq*8);
        acc[nt] = __builtin_amdgcn_mfma_f32_16x16x32_f16(af, bf, acc[nt], 0,0,0);
      }
    }
    #pragma unroll
    for (int r=0;r<4;r++){
      int jl = 16*wv + 4*kq + r;
      float av[4]; float cm=-1e30f;
      #pragma unroll
      for (int nt=0;nt<4;nt++){ av[nt]=acc[nt][r]; cm=fmaxf(cm,av[nt]); }
      cm = wmax16(cm);
      float old = mx_s[jl], nm = fmaxf(old, cm);
      float ds=0.f, nsum=0.f;
      const size_t srow = ((size_t)b*512 + jt*64 + jl)*512;
      #pragma unroll
      for (int nt=0;nt<4;nt++){
        float e = __expf(av[nt]-nm);
        float sc = (float)scT[srow + i0 + nt*16 + l15];
        ds += e; nsum += sc*e;
      }
      ds = wsum16(ds); nsum = wsum16(nsum);
      if (l15==0){
        float fac = __expf(old-nm);
        den_s[jl] = den_s[jl]*fac + ds;
        num_s[jl] = num_s[jl]*fac + nsum;
        mx_s[jl] = nm;
      }
    }
  }
  __syncthreads();
  if (tid<64){
    size_t idx = (((size_t)b*512) + jt*64 + tid)*2 + is;
    pmx[idx]=mx_s[tid]; pden[idx]=den_s[tid]; pnum[idx]=num_s[tid];
  }
}

__global__ void k_comb2(const float* __restrict__ pmx, const float* __restrict__ pden,
                        const float* __restrict__ pnum, float* __restrict__ out){
  const int b = blockIdx.x, j = threadIdx.x;    // 32 x 512
  size_t base = ((size_t)b*512 + j)*2;
  float m0=pmx[base], m1=pmx[base+1];
  float m = fmaxf(m0,m1);
  float e0=__expf(m0-m), e1=__expf(m1-m);
  float den = pden[base]*e0 + pden[base+1]*e1;
  float num = pnum[base]*e0 + pnum[base+1]*e1;
  float lp = __logf(num) - __logf(den);
  __shared__ float red[512];
  red[j] = lp;
  __syncthreads();
  for (int st=256; st>0; st>>=1){ if (j<st) red[j]+=red[j+st]; __syncthreads(); }
  if (j==0) atomicAdd(out, -red[0]);
}

// ---------------- LSTM v7: gate-packed i8 MFMA, 2 units/thread, no gate selects ----------------
// 512 thr, 8 waves. Wave w holds tiles t8=0..7 (tile row r15 = u4*4+g, unit = w*32+t8*4+u4),
// 32 frags = 128 AGPR. B cols replicated: col's seq = col&3. From D, lane (kq,l15) reg e gets
// gate e of unit w*32+t8*4+kq. p=l15>>2 splits the 8 tiles: thread owns uA = w*32+8p+kq
// (tile 2p) and uB = uA+4 (tile 2p+1), seq s=l15&3.
// h8 chunk-interleaved: byte(unit u, seq s) at ((u>>4)*4+s)*16 + (u&15) -> b128 conflict-free.
// U permuted unit-major (col' = unit*4+gate) -> one b64 read per unit.
DEVI void lstm_core(char* smem, const f16* U, const i32x4* Wq, const u32* ws,
                    u16* hout, float* hTcT, u16* hdec0, int nsteps, int mode, int bid)
{
  f16* Ub  = (f16*)smem;             // 2 buffers x 4*1032 halves = 16512 B
  char* h8b = smem + 16512;          // 2 buffers x 1024 B
  const int tid = threadIdx.x;
  const int lane = tid & 63, w = tid >> 6;
  const int l15 = lane & 15, kq = lane >> 4;
  const int s = l15 & 3, p = l15 >> 2;
  const int uA = w*32 + 8*p + kq;
  const int uB = uA + 4;

  int dir = 0, b0;
  if (mode == 0){ dir = bid >> 3; b0 = (bid & 7)*4; }
  else b0 = bid*4;

  const float zscale = __uint_as_float(ws[0]) * (1.f/(127.f*127.f));

  i32x4 aw[32];
  #pragma unroll
  for (int f=0; f<32; f++) aw[f] = Wq[(size_t)(w*32 + f)*64 + lane];

  float cA = 0.f, cB = 0.f;
  if (mode == 0){
    ((u32*)h8b)[tid] = 0u;           // 512 words = both buffers
  } else {
    const float* hp = hTcT + (size_t)(b0+s)*512;
    float hA = hp[uA], hB = hp[uB];
    cA = hp[256 + uA]; cB = hp[256 + uB];
    h8b[((uA>>4)*4 + s)*16 + (uA&15)] = (char)(int)__builtin_rintf(hA*127.f);
    h8b[((uB>>4)*4 + s)*16 + (uB&15)] = (char)(int)__builtin_rintf(hB*127.f);
  }

  const int s_st = tid >> 7, col = (tid & 127)*8;
  {
    int tp0 = dir ? (nsteps-1) : 0;
    *(int4*)&Ub[s_st*1032 + col] = *(const int4*)(U + ((size_t)(b0+s_st)*512 + tp0)*1024 + col);
  }
  __syncthreads();

  int cur = 0;
  #pragma unroll 1
  for (int t=0; t<nsteps; ++t){
    const int tpos = dir ? (nsteps-1-t) : t;
    int tn = dir ? (nsteps-2-t >= 0 ? nsteps-2-t : 0) : (t+1 < nsteps ? t+1 : nsteps-1);
    int4 pu = *(const int4*)(U + ((size_t)(b0+s_st)*512 + tn)*1024 + col);

    const char* hc = h8b + cur*1024;
    i32x4 bf[4];
    #pragma unroll
    for (int kt=0; kt<4; kt++)
      bf[kt] = *(const i32x4*)(hc + ((kt*4 + kq)*4 + s)*16);

    i32x4 acc[8];
    #pragma unroll
    for (int t8=0; t8<8; t8++){
      i32x4 d = {0,0,0,0};
      #pragma unroll
      for (int kt=0; kt<4; kt++)
        d = __builtin_amdgcn_mfma_i32_16x16x64_i8(aw[t8*4+kt], bf[kt], d, 0,0,0);
      acc[t8] = d;
    }

    // pick tiles 2p (uA) and 2p+1 (uB)
    i32x4 vA, vB;
    #pragma unroll
    for (int e=0; e<4; e++){
      int x0 = (p&1) ? acc[2][e] : acc[0][e];
      int x1 = (p&1) ? acc[6][e] : acc[4][e];
      vA[e] = (p&2) ? x1 : x0;
      int y0 = (p&1) ? acc[3][e] : acc[1][e];
      int y1 = (p&1) ? acc[7][e] : acc[5][e];
      vB[e] = (p&2) ? y1 : y0;
    }

    const f16* upA = Ub + cur*4128 + s*1032 + uA*4;
    const f16* upB = Ub + cur*4128 + s*1032 + uB*4;
    float hA_, hB_;
    {
      float z0 = fmaf((float)vA[0], zscale, (float)upA[0]);
      float z1 = fmaf((float)vA[1], zscale, (float)upA[1]);
      float z2 = fmaf((float)vA[2], zscale, (float)upA[2]);
      float z3 = fmaf((float)vA[3], zscale, (float)upA[3]);
      cA = sig_f(z1)*cA + sig_f(z0)*tanh_f(z2);
      hA_ = sig_f(z3)*tanh_f(cA);
    }
    {
      float z0 = fmaf((float)vB[0], zscale, (float)upB[0]);
      float z1 = fmaf((float)vB[1], zscale, (float)upB[1]);
      float z2 = fmaf((float)vB[2], zscale, (float)upB[2]);
      float z3 = fmaf((float)vB[3], zscale, (float)upB[3]);
      cB = sig_f(z1)*cB + sig_f(z0)*tanh_f(z2);
      hB_ = sig_f(z3)*tanh_f(cB);
    }

    const int nxt = cur ^ 1;
    char* hn = h8b + nxt*1024;
    hn[((uA>>4)*4 + s)*16 + (uA&15)] = (char)(int)__builtin_rintf(hA_*127.f);
    hn[((uB>>4)*4 + s)*16 + (uB&15)] = (char)(int)__builtin_rintf(hB_*127.f);
    *(int4*)&Ub[nxt*4128 + s_st*1032 + col] = pu;

    f16 fA = (f16)hA_, fB = (f16)hB_;
    if (mode == 0){
      u16* hr = hout + ((size_t)(b0+s)*512 + tpos)*512 + dir*256;
      hr[uA] = __builtin_bit_cast(u16, fA);
      hr[uB] = __builtin_bit_cast(u16, fB);
      if (!dir && t == nsteps-1){
        hdec0[(size_t)(b0+s)*512*256 + uA] = __builtin_bit_cast(u16, fA);
        hdec0[(size_t)(b0+s)*512*256 + uB] = __builtin_bit_cast(u16, fB);
        float* hp = hTcT + (size_t)(b0+s)*512;
        hp[uA] = hA_; hp[uB] = hB_;
        hp[256+uA] = cA; hp[256+uB] = cB;
      }
    } else {
      u16* hr = hout + ((size_t)(b0+s)*512 + (t+1))*256;
      hr[uA] = __builtin_bit_cast(u16, fA);
      hr[uB] = __builtin_bit_cast(u16, fB);
    }
    __syncthreads();
    cur = nxt;
  }
}

// ---------------- mega dispatches (no intra-dispatch dependencies) ----------------
__global__ __launch_bounds__(512,2) void k_mega_enc(
    const f16* __restrict__ Uenc, const i32x4* __restrict__ Wqe, const u32* __restrict__ wse,
    u16* __restrict__ henh, float* __restrict__ hTcT, u16* __restrict__ hdec0,
    const f16* __restrict__ tf, const f16* __restrict__ gdT,
    float* __restrict__ mxp, float* __restrict__ sep,
    const f16* __restrict__ yemb, const f16* __restrict__ Wihd,
    const float* __restrict__ db, f16* __restrict__ Udec)
{
  __shared__ __align__(16) char smem[45056];
  const int bid = blockIdx.x;
  const int tid = threadIdx.x;
  if (bid < 16){
    lstm_core(smem, Uenc, Wqe, wse, henh, hTcT, hdec0, 512, 0, bid);
  } else if (bid < 1040){
    int vb = bid - 16;                 // 0..1023
    int mt = vb >> 2;                  // 0..255
    int ns = vb & 3;                   // 0..3
    pass1_body(tid, mt, ns, tf, gdT, mxp, sep,
               (f16*)smem, (f16*)(smem + 33792), (float*)(smem + 44032), (float*)(smem + 44544));
  } else {
    int vb = bid - 1040;               // 0..2047
    int half = tid >> 8, t256 = tid & 255;
    int vbm = vb >> 4, ny = vb & 15;
    int m0 = (vbm*2 + half)*64;
    int n0 = ny*64;
    char* base = smem + half*10240;
    ku_body(t256, m0, n0, yemb, Wihd, db, Udec, (f16*)base, (f16*)(base + 5120));
  }
}

__global__ __launch_bounds__(512,2) void k_mega_dec(
    const f16* __restrict__ Udec, const i32x4* __restrict__ Wqd, const u32* __restrict__ wsd,
    u16* __restrict__ hdec, float* __restrict__ hTcT,
    const f16* __restrict__ tf, const f16* __restrict__ gdT, const int* __restrict__ ys,
    const float* __restrict__ mx, const float* __restrict__ se, f16* __restrict__ scT,
    const f16* __restrict__ henh, const f16* __restrict__ Tf, f16* __restrict__ Th)
{
  __shared__ __align__(16) char smem[24576];
  const int bid = blockIdx.x;
  const int tid = threadIdx.x;
  if (bid < 8){
    lstm_core(smem, Udec, Wqd, wsd, hdec, hTcT, hdec, 511, 1, bid);
  } else if (bid < 1032){
    int vb = bid - 8;                  // 0..1023
    int half = tid >> 8, t256 = tid & 255;
    int b = vb >> 5, rem = vb & 31;
    int jt = rem >> 2, it = (rem & 3)*2 + half;
    char* base = smem + half*10496;
    pass2_body(t256, it, jt, b, tf, gdT, ys, mx, se, scT,
               (f16*)base, (f16*)(base + 5120), (int*)(base + 10240));
  } else {
    int vb = bid - 1032;               // 0..511
    int half = tid >> 8, t256 = tid & 255;
    int m0 = ((vb >> 2)*2 + half)*64;
    int n0 = (vb & 3)*64;
    char* base = smem + half*10240;
    th_body(t256, m0, n0, henh, Tf, Th, (f16*)base, (f16*)(base + 5120));
  }
}

// ---------------- host ----------------
extern "C" void kernel_launch(void* const* d_in, const int* in_sizes, int n_in,
                              void* d_out, int out_size, void* d_ws, size_t ws_size,
                              hipStream_t stream)
{
  (void)in_sizes; (void)n_in; (void)out_size;
  const int*   xs    = (const int*)d_in[0];
  const int*   ys    = (const int*)d_in[1];
  const float* gemb  = (const float*)d_in[2];
  const float* gconv = (const float*)d_in[3];
  const float* gdec  = (const float*)d_in[4];
  const float* eemb  = (const float*)d_in[5];
  const float* demb  = (const float*)d_in[6];
  const float* eWih  = (const float*)d_in[7];
  const float* eWhh  = (const float*)d_in[8];
  const float* eb    = (const float*)d_in[9];
  const float* dWih  = (const float*)d_in[10];
  const float* dWhh  = (const float*)d_in[11];
  const float* db    = (const float*)d_in[12];
  const float* Tm    = (const float*)d_in[13];

  char* wsb = (char*)d_ws;
  size_t off = 0;
  auto take = [&](size_t bytes)->char*{ char* p = wsb + off; off += (bytes + 255) & ~(size_t)255; return p; };
  f16* epad  = (f16*)take((size_t)32*516*256*2);
  f16* tf    = (f16*)take((size_t)32*512*256*2);
  f16* xemb  = (f16*)take((size_t)32*512*128*2);
  f16* yemb  = (f16*)take((size_t)32*512*128*2);
  f16* Uenc  = (f16*)take((size_t)32*512*1024*2);
  f16* Udec  = (f16*)take((size_t)32*512*1024*2);
  f16* henh  = (f16*)take((size_t)32*512*512*2);
  f16* hdec  = (f16*)take((size_t)32*512*256*2);
  f16* Th    = (f16*)take((size_t)32*512*256*2);
  f16* scT   = (f16*)take((size_t)32*512*512*2);
  float* mx  = (float*)take((size_t)16384*4);
  float* se  = (float*)take((size_t)16384*4);
  float* mxp = (float*)take((size_t)4*16384*4);
  float* sep = (float*)take((size_t)4*16384*4);
  float* pmx = (float*)take((size_t)32*512*2*4);
  float* pden= (float*)take((size_t)32*512*2*4);
  float* pnum= (float*)take((size_t)32*512*2*4);
  float* hTcT= (float*)take((size_t)32*512*4);
  f16* Wihe  = (f16*)take((size_t)1024*128*2);
  f16* Wihd  = (f16*)take((size_t)1024*128*2);
  f16* Tf    = (f16*)take((size_t)256*512*2);
  f16* gcT   = (f16*)take((size_t)256*1280*2);
  f16* gdT   = (f16*)take((size_t)2048*256*2);
  i32x4* Wq8e = (i32x4*)take((size_t)256*64*16);
  i32x4* Wq8d = (i32x4*)take((size_t)256*64*16);
  u32* wsc   = (u32*)take(8);
  if (off > ws_size) return;

  hipMemsetAsync(d_out, 0, sizeof(float), stream);
  hipMemsetAsync(wsc, 0, 8, stream);

  // prep
  k_cvt<<<dim3(512),  256, 0, stream>>>(eWih, Wihe, 1024*128);
  k_cvt<<<dim3(512),  256, 0, stream>>>(dWih, Wihd, 1024*128);
  k_cvt<<<dim3(512),  256, 0, stream>>>(Tm,   Tf,   256*512);
  k_gconvT<<<dim3(1280), 256, 0, stream>>>(gconv, gcT);
  k_gdecT <<<dim3(2048), 256, 0, stream>>>(gdec, gdT);
  k_wmax<<<dim3(256), 256, 0, stream>>>(eWhh, wsc + 0);
  k_wmax<<<dim3(256), 256, 0, stream>>>(dWhh, wsc + 1);
  k_wq8<<<dim3(256), 64, 0, stream>>>(eWhh, wsc + 0, Wq8e);
  k_wq8<<<dim3(256), 64, 0, stream>>>(dWhh, wsc + 1, Wq8d);
  k_epad<<<dim3(32*516), 256, 0, stream>>>(xs, gemb, epad);
  k_embx<<<dim3(2*32*512), 128, 0, stream>>>(xs, ys, eemb, demb, xemb, yemb);

  // tf and enc input-gates (needed by mega_enc)
  k_conv<<<dim3(256,4), 256, 0, stream>>>(epad, gcT, tf);
  k_u<<<dim3(256,16), 256, 0, stream>>>(xemb, Wihe, eb, Uenc);

  // mega-enc: [0,16) lstm_enc | [16,1040) pass1 | [1040,3088) k_u dec (dual 256-thr teams)
  k_mega_enc<<<dim3(3088), 512, 0, stream>>>(Uenc, Wq8e, wsc + 0, (u16*)henh, hTcT, (u16*)hdec,
                                             tf, gdT, mxp, sep, yemb, Wihd, db, Udec);
  k_comb1<<<dim3(64), 256, 0, stream>>>(mxp, sep, mx, se);

  // mega-dec: [0,8) lstm_dec | [8,1032) pass2 | [1032,1544) k_th
  k_mega_dec<<<dim3(1544), 512, 0, stream>>>(Udec, Wq8d, wsc + 1, (u16*)hdec, hTcT,
                                             tf, gdT, ys, mx, se, scT, henh, Tf, Th);

  k_final<<<dim3(2,8,32), 256, 0, stream>>>(hdec, Th, scT, pmx, pden, pnum);
  k_comb2<<<dim3(32), 512, 0, stream>>>(pmx, pden, pnum, (float*)d_out);
}